// Round 3
// baseline (13639.185 us; speedup 1.0000x reference)
//
#include <hip/hip_runtime.h>
#include <cstdint>
#include <cstddef>

#define BATCH 128
#define INF   64
#define OUTF  16
#define SEQ   512
#define FUT   96
#define HID   512
#define G4    2048   // 4*HID
#define PROJ  48

// decoder decomposition
#define DRG 8    // unit groups (64 units each)
#define DBG 8    // batch groups (16 batches each)
#define DUP 64   // units per rg
#define DBP 16   // batches per bg

__device__ __forceinline__ float fsigmoid(float x) {
    float e = __builtin_amdgcn_exp2f(-1.4426950408889634f * x);
    return __builtin_amdgcn_rcpf(1.0f + e);
}
__device__ __forceinline__ float ftanh(float x) {
    float e = __builtin_amdgcn_exp2f(2.8853900817779268f * x);
    return 1.0f - 2.0f * __builtin_amdgcn_rcpf(1.0f + e);
}

// barrier among the DRG WGs of one batch-group chain; per-WG flag slots
// (64B apart), monotonically increasing phase, zeroed by memset each launch.
__device__ __forceinline__ void bsync(unsigned* slots, int rg, unsigned phase, int tid) {
    __syncthreads();   // all WG threads done (incl. vmcnt drain before barrier)
    if (tid == 0)
        __hip_atomic_store(&slots[rg * 16], phase, __ATOMIC_RELEASE, __HIP_MEMORY_SCOPE_AGENT);
    if (tid < DRG) {
        while (__hip_atomic_load(&slots[tid * 16], __ATOMIC_RELAXED, __HIP_MEMORY_SCOPE_AGENT) < phase)
            __builtin_amdgcn_s_sleep(2);
    }
    __builtin_amdgcn_fence(__ATOMIC_ACQUIRE, "agent");
    __syncthreads();
}

// ---------------- init: zero states, build first_prev ----------------
__global__ void k_init(const float* __restrict__ x, float* __restrict__ hs,
                       float* __restrict__ cs, float* __restrict__ prev) {
    int idx = blockIdx.x * 256 + threadIdx.x;
    if (idx < 2 * BATCH * PROJ) hs[idx] = 0.f;
    if (idx < 2 * BATCH * HID)  cs[idx] = 0.f;
    if (idx < BATCH * PROJ) {
        int b = idx / PROJ, p = idx % PROJ;
        prev[idx] = x[(size_t)b * INF * SEQ + (size_t)p * SEQ + (SEQ - 1)];
    }
}

// ---------------- transpose x[b][k][t] -> xT[(t*B+b)*INF + k] ----------------
__global__ void k_transpose(const float* __restrict__ x, float* __restrict__ xT) {
    __shared__ float tile[32][33];
    int b  = blockIdx.z;
    int t0 = blockIdx.x * 32;
    int k0 = blockIdx.y * 32;
    int tx = threadIdx.x, ty = threadIdx.y; // 32 x 8
    #pragma unroll
    for (int i = 0; i < 4; ++i) {
        int k = k0 + ty + 8 * i;
        tile[ty + 8 * i][tx] = x[(size_t)b * INF * SEQ + (size_t)k * SEQ + t0 + tx];
    }
    __syncthreads();
    #pragma unroll
    for (int i = 0; i < 4; ++i) {
        int t = t0 + ty + 8 * i;
        xT[((size_t)t * BATCH + b) * INF + k0 + tx] = tile[tx][ty + 8 * i];
    }
}

// ---------------- input-gates GEMM v2: K-resident (K=64 or 48) ----------------
// BM=BN=128, 512 threads, 8 rows x 4 cols per thread, single stage + 1 barrier.
template<int K>
__global__ __launch_bounds__(512) void k_gates2(
    const float* __restrict__ A, int row0,
    const float* __restrict__ W, const float* __restrict__ bih,
    const float* __restrict__ bhh, float* __restrict__ G)
{
    __shared__ float Ast[128][K + 4];
    __shared__ float Wst[K][132];
    const int tid = threadIdx.x;
    const int rbase = blockIdx.x * 128;
    const int cb = blockIdx.y * 128;

    // stage A (row-major, padded) -- coalesced float4 loads
    #pragma unroll
    for (int i = 0; i < K / 16; ++i) {
        int idx = tid + i * 512;
        int r = idx / (K / 4), kq = idx % (K / 4);
        float4 v = *reinterpret_cast<const float4*>(&A[(size_t)(row0 + rbase + r) * K + kq * 4]);
        *reinterpret_cast<float4*>(&Ast[r][kq * 4]) = v;
    }
    // stage W transposed to [k][c]
    #pragma unroll
    for (int i = 0; i < K / 16; ++i) {
        int idx = tid + i * 512;
        int c = idx / (K / 4), kq = idx % (K / 4);
        float4 v = *reinterpret_cast<const float4*>(&W[(size_t)(cb + c) * K + kq * 4]);
        Wst[kq * 4 + 0][c] = v.x; Wst[kq * 4 + 1][c] = v.y;
        Wst[kq * 4 + 2][c] = v.z; Wst[kq * 4 + 3][c] = v.w;
    }
    __syncthreads();

    const int cg = tid & 31;   // cols cg*4 (lane-fast -> coalesced C stores)
    const int rg = tid >> 5;   // rows rg*8 (same for 32-lane half -> A broadcast)
    float acc[8][4];
    #pragma unroll
    for (int j = 0; j < 8; ++j)
        #pragma unroll
        for (int i = 0; i < 4; ++i) acc[j][i] = 0.f;

    #pragma unroll
    for (int k4 = 0; k4 < K / 4; ++k4) {
        float4 w0 = *reinterpret_cast<const float4*>(&Wst[k4 * 4 + 0][cg * 4]);
        float4 w1 = *reinterpret_cast<const float4*>(&Wst[k4 * 4 + 1][cg * 4]);
        float4 w2 = *reinterpret_cast<const float4*>(&Wst[k4 * 4 + 2][cg * 4]);
        float4 w3 = *reinterpret_cast<const float4*>(&Wst[k4 * 4 + 3][cg * 4]);
        #pragma unroll
        for (int j = 0; j < 8; ++j) {
            float4 a = *reinterpret_cast<const float4*>(&Ast[rg * 8 + j][k4 * 4]);
            acc[j][0] += a.x * w0.x + a.y * w1.x + a.z * w2.x + a.w * w3.x;
            acc[j][1] += a.x * w0.y + a.y * w1.y + a.z * w2.y + a.w * w3.y;
            acc[j][2] += a.x * w0.z + a.y * w1.z + a.z * w2.z + a.w * w3.z;
            acc[j][3] += a.x * w0.w + a.y * w1.w + a.z * w2.w + a.w * w3.w;
        }
    }
    int c0 = cb + cg * 4;
    float4 bv;
    bv.x = bih[c0] + bhh[c0];     bv.y = bih[c0 + 1] + bhh[c0 + 1];
    bv.z = bih[c0 + 2] + bhh[c0 + 2]; bv.w = bih[c0 + 3] + bhh[c0 + 3];
    #pragma unroll
    for (int j = 0; j < 8; ++j) {
        float4 o;
        o.x = acc[j][0] + bv.x; o.y = acc[j][1] + bv.y;
        o.z = acc[j][2] + bv.z; o.w = acc[j][3] + bv.w;
        *reinterpret_cast<float4*>(&G[(size_t)(rbase + rg * 8 + j) * G4 + c0]) = o;
    }
}

// ---------------- encoder recurrent phase: one WG per batch element ----------------
__global__ __launch_bounds__(512) void k_rnn(
    const float* __restrict__ G,
    const float* __restrict__ Whh,
    const float* __restrict__ Whr,
    float* __restrict__ Hout,
    float* __restrict__ h_state,
    float* __restrict__ c_state,
    int t0, int nt)
{
    __shared__ float whr_lo[PROJ][256];
    __shared__ __align__(16) float ht_lds[HID];
    __shared__ __align__(16) float h_cur[PROJ];
    int b = blockIdx.x;
    int j = threadIdx.x;
    int wave = j >> 6, lane = j & 63;

    float wI[PROJ], wF[PROJ], wG[PROJ], wO[PROJ];
    #pragma unroll
    for (int k4 = 0; k4 < 12; ++k4) {
        float4 vi = *reinterpret_cast<const float4*>(&Whh[(size_t)j * PROJ + 4 * k4]);
        float4 vf = *reinterpret_cast<const float4*>(&Whh[(size_t)(j + HID) * PROJ + 4 * k4]);
        float4 vg = *reinterpret_cast<const float4*>(&Whh[(size_t)(j + 2 * HID) * PROJ + 4 * k4]);
        float4 vo = *reinterpret_cast<const float4*>(&Whh[(size_t)(j + 3 * HID) * PROJ + 4 * k4]);
        wI[4*k4+0]=vi.x; wI[4*k4+1]=vi.y; wI[4*k4+2]=vi.z; wI[4*k4+3]=vi.w;
        wF[4*k4+0]=vf.x; wF[4*k4+1]=vf.y; wF[4*k4+2]=vf.z; wF[4*k4+3]=vf.w;
        wG[4*k4+0]=vg.x; wG[4*k4+1]=vg.y; wG[4*k4+2]=vg.z; wG[4*k4+3]=vg.w;
        wO[4*k4+0]=vo.x; wO[4*k4+1]=vo.y; wO[4*k4+2]=vo.z; wO[4*k4+3]=vo.w;
    }
    for (int idx = j; idx < PROJ * 256; idx += 512) {
        int p = idx >> 8, jj = idx & 255;
        whr_lo[p][jj] = Whr[(size_t)p * HID + jj];
    }
    float wr[6][4];
    #pragma unroll
    for (int q = 0; q < 6; ++q)
        #pragma unroll
        for (int m = 0; m < 4; ++m)
            wr[q][m] = Whr[(size_t)(wave * 6 + q) * HID + 256 + lane + 64 * m];

    float c = c_state[(size_t)b * HID + j];
    if (j < PROJ) h_cur[j] = h_state[(size_t)b * PROJ + j];
    __syncthreads();

    const float* Gr = G + (size_t)b * G4;
    float gi = Gr[j], gf = Gr[j + HID], gg = Gr[j + 2 * HID], go = Gr[j + 3 * HID];

    for (int ct = 0; ct < nt; ++ct) {
        float ai = gi, af = gf, ag = gg, ao = go;
        #pragma unroll
        for (int k4 = 0; k4 < 12; ++k4) {
            float4 h4 = *reinterpret_cast<const float4*>(&h_cur[4 * k4]);
            ai += wI[4*k4+0]*h4.x + wI[4*k4+1]*h4.y + wI[4*k4+2]*h4.z + wI[4*k4+3]*h4.w;
            af += wF[4*k4+0]*h4.x + wF[4*k4+1]*h4.y + wF[4*k4+2]*h4.z + wF[4*k4+3]*h4.w;
            ag += wG[4*k4+0]*h4.x + wG[4*k4+1]*h4.y + wG[4*k4+2]*h4.z + wG[4*k4+3]*h4.w;
            ao += wO[4*k4+0]*h4.x + wO[4*k4+1]*h4.y + wO[4*k4+2]*h4.z + wO[4*k4+3]*h4.w;
        }
        if (ct + 1 < nt) {
            const float* Gn = G + ((size_t)(ct + 1) * BATCH + b) * G4;
            gi = Gn[j]; gf = Gn[j + HID]; gg = Gn[j + 2 * HID]; go = Gn[j + 3 * HID];
        }
        float si = fsigmoid(ai), sf = fsigmoid(af), so = fsigmoid(ao), tg = ftanh(ag);
        c = sf * c + si * tg;
        ht_lds[j] = so * ftanh(c);
        __syncthreads();
        float rq[6];
        #pragma unroll
        for (int q = 0; q < 6; ++q) {
            int p = wave * 6 + q;
            float s = 0.f;
            #pragma unroll
            for (int m = 0; m < 4; ++m) s += whr_lo[p][lane + 64 * m] * ht_lds[lane + 64 * m];
            #pragma unroll
            for (int m = 0; m < 4; ++m) s += wr[q][m] * ht_lds[256 + lane + 64 * m];
            #pragma unroll
            for (int o = 32; o; o >>= 1) s += __shfl_xor(s, o, 64);
            rq[q] = s;
        }
        if (lane == 0) {
            int t = t0 + ct;
            #pragma unroll
            for (int q = 0; q < 6; ++q) {
                h_cur[wave * 6 + q] = rq[q];
                Hout[((size_t)t * BATCH + b) * PROJ + wave * 6 + q] = rq[q];
            }
        }
        __syncthreads();
    }
    c_state[(size_t)b * HID + j] = c;
    if (j < PROJ) h_state[(size_t)b * PROJ + j] = h_cur[j];
}

// ---------------- decoder v2: 8rg x 8bg, partial-proj, 2 syncs/step ----------------
__global__ __launch_bounds__(512) void k_dec2(
    const float* __restrict__ xdec,
    const float* __restrict__ Wih0, const float* __restrict__ Whh0,
    const float* __restrict__ bih0, const float* __restrict__ bhh0,
    const float* __restrict__ Whr0,
    const float* __restrict__ Wih1, const float* __restrict__ Whh1,
    const float* __restrict__ bih1, const float* __restrict__ bhh1,
    const float* __restrict__ Whr1,
    const float* __restrict__ hs, const float* __restrict__ cs,
    const float* __restrict__ prev0,
    float* __restrict__ PPa,    // [2][DRG][BATCH][48]
    float* __restrict__ PPb,    // [DRG][BATCH][48]
    float* __restrict__ PRED,   // [FUT][BATCH][48]
    unsigned* __restrict__ bar) // [DBG][DRG*16]
{
    const int bg  = blockIdx.x & 7;   // chain id; &7 targets same-XCD placement
    const int rg  = blockIdx.x >> 3;
    const int tid = threadIdx.x;
    // gate mapping: 256 rows x 2 k-halves
    const int r  = tid >> 1;
    const int kh = tid & 1;
    const int g  = r >> 6;
    const int u  = r & 63;
    const int grow = g * HID + rg * DUP + u;
    // c-update mapping: 64 units x 8 batches (x2)
    const int u2 = tid >> 3;
    const int b2 = tid & 7;
    const int uglob = rg * DUP + u2;
    // proj mapping
    const int w = tid >> 6, lane = tid & 63;

    __shared__ float inp0[DBP][120];  // [h0(0..47) | prev(48..95) | x(96..111)]
    __shared__ float h1b[DBP][52];
    __shared__ float h0n[DBP][52];
    __shared__ float xch[4][DUP][17];
    __shared__ float htl[DBP][68];
    __shared__ float wsl0[PROJ][68];
    __shared__ float wsl1[PROJ][68];

    // ---- one-time weight preload ----
    float W0v[56], W1v[48];
    #pragma unroll
    for (int kk = 0; kk < 56; ++kk) {
        int k = kh * 56 + kk;
        W0v[kk] = (k < 48) ? Whh0[(size_t)grow * 48 + k]
                           : Wih0[(size_t)grow * 64 + (k - 48)];
    }
    #pragma unroll
    for (int kk = 0; kk < 48; ++kk) {
        int k = kh * 48 + kk;
        W1v[kk] = (k < 48) ? Whh1[(size_t)grow * 48 + k]
                           : Wih1[(size_t)grow * 48 + (k - 48)];
    }
    for (int i = tid; i < PROJ * DUP; i += 512) {
        int p = i >> 6, uu = i & 63;
        wsl0[p][uu] = Whr0[(size_t)p * HID + rg * DUP + uu];
        wsl1[p][uu] = Whr1[(size_t)p * HID + rg * DUP + uu];
    }
    float bs0[4], bs1[4];
    #pragma unroll
    for (int gg = 0; gg < 4; ++gg) {
        bs0[gg] = bih0[gg * HID + uglob] + bhh0[gg * HID + uglob];
        bs1[gg] = bih1[gg * HID + uglob] + bhh1[gg * HID + uglob];
    }
    float c0[2], c1[2];
    #pragma unroll
    for (int hh = 0; hh < 2; ++hh) {
        int bglob = bg * DBP + b2 + 8 * hh;
        c0[hh] = cs[(size_t)bglob * HID + uglob];
        c1[hh] = cs[(size_t)(BATCH + bglob) * HID + uglob];
    }
    __syncthreads();

    unsigned* slots = bar + bg * (DRG * 16);
    unsigned phase = 0;

    for (int t = 0; t < FUT; ++t) {
        // ================= PHASE A =================
        if (t == 0) {
            for (int i = tid; i < DBP * PROJ; i += 512) {
                int b = i / PROJ, p = i % PROJ;
                int bglob = bg * DBP + b;
                inp0[b][p]      = hs[(size_t)bglob * PROJ + p];
                inp0[b][48 + p] = prev0[(size_t)bglob * PROJ + p];
                h1b[b][p]       = hs[(size_t)(BATCH + bglob) * PROJ + p];
            }
        } else {
            const float* pa = PPa + (size_t)((t - 1) & 1) * (DRG * BATCH * PROJ);
            for (int i = tid; i < 2 * DBP * PROJ; i += 512) {
                int which = (i >= DBP * PROJ);
                int idx = which ? i - DBP * PROJ : i;
                int b = idx / PROJ, p = idx % PROJ;
                int bglob = bg * DBP + b;
                const float* src = which ? PPb : pa;
                float s = 0.f;
                #pragma unroll
                for (int rr = 0; rr < DRG; ++rr)
                    s += src[(size_t)rr * (BATCH * PROJ) + (size_t)bglob * PROJ + p];
                if (which) { inp0[b][48 + p] = s; h1b[b][p] = s; }
                else        inp0[b][p] = s;
            }
        }
        if (tid < DBP * OUTF) {
            int b = tid >> 4, f = tid & 15;
            inp0[b][96 + f] = xdec[(size_t)(bg * DBP + b) * (OUTF * FUT) + (size_t)f * FUT + t];
        }
        __syncthreads();
        // PRED[t-1] (this rg writes its 2 batches)
        if (t > 0 && tid < 2 * PROJ) {
            int bb = tid / PROJ, p = tid % PROJ;
            int bl = 2 * rg + bb;
            PRED[((size_t)(t - 1) * BATCH + bg * DBP + bl) * PROJ + p] = h1b[bl][p];
        }
        // ---- L0 gates ----
        {
            float acc[DBP];
            #pragma unroll
            for (int b = 0; b < DBP; ++b) acc[b] = 0.f;
            const float* srcA = &inp0[0][0] + kh * 56;
            #pragma unroll
            for (int i4 = 0; i4 < 14; ++i4) {
                float w0 = W0v[i4*4], w1 = W0v[i4*4+1], w2 = W0v[i4*4+2], w3 = W0v[i4*4+3];
                #pragma unroll
                for (int b = 0; b < DBP; ++b) {
                    float4 xv = *reinterpret_cast<const float4*>(&srcA[b * 120 + i4 * 4]);
                    acc[b] += w0*xv.x + w1*xv.y + w2*xv.z + w3*xv.w;
                }
            }
            #pragma unroll
            for (int b = 0; b < DBP; ++b) acc[b] += __shfl_xor(acc[b], 1, 64);
            if (kh == 0) {
                #pragma unroll
                for (int b = 0; b < DBP; ++b) xch[g][u][b] = acc[b];
            }
        }
        __syncthreads();
        // ---- c0 update + ht0 ----
        #pragma unroll
        for (int hh = 0; hh < 2; ++hh) {
            int b = b2 + 8 * hh;
            float gi = xch[0][u2][b] + bs0[0];
            float gf = xch[1][u2][b] + bs0[1];
            float gc = xch[2][u2][b] + bs0[2];
            float go = xch[3][u2][b] + bs0[3];
            float si = fsigmoid(gi), sf = fsigmoid(gf), so = fsigmoid(go), tg = ftanh(gc);
            c0[hh] = sf * c0[hh] + si * tg;
            htl[b][u2] = so * ftanh(c0[hh]);
        }
        __syncthreads();
        // ---- partial proj0 over this rg's 64-unit slice ----
        if (lane < PROJ) {
            float* dstb = PPa + (size_t)(t & 1) * (DRG * BATCH * PROJ)
                        + (size_t)rg * (BATCH * PROJ);
            #pragma unroll
            for (int bb = 0; bb < 2; ++bb) {
                int b = 2 * w + bb;
                float s = 0.f;
                #pragma unroll
                for (int u4 = 0; u4 < 16; ++u4) {
                    float4 wv = *reinterpret_cast<const float4*>(&wsl0[lane][u4 * 4]);
                    float4 hv = *reinterpret_cast<const float4*>(&htl[b][u4 * 4]);
                    s += wv.x*hv.x + wv.y*hv.y + wv.z*hv.z + wv.w*hv.w;
                }
                dstb[(size_t)(bg * DBP + b) * PROJ + lane] = s;
            }
        }
        phase += 1;
        bsync(slots, rg, phase, tid);

        // ================= PHASE B =================
        {
            const float* pa2 = PPa + (size_t)(t & 1) * (DRG * BATCH * PROJ);
            for (int i = tid; i < DBP * PROJ; i += 512) {
                int b = i / PROJ, p = i % PROJ;
                float s = 0.f;
                #pragma unroll
                for (int rr = 0; rr < DRG; ++rr)
                    s += pa2[(size_t)rr * (BATCH * PROJ) + (size_t)(bg * DBP + b) * PROJ + p];
                h0n[b][p] = s;
            }
        }
        __syncthreads();
        // ---- L1 gates (kh=0: Whh1 x h1b, kh=1: Wih1 x h0n) ----
        {
            float acc[DBP];
            #pragma unroll
            for (int b = 0; b < DBP; ++b) acc[b] = 0.f;
            const float* srcB = kh ? &h0n[0][0] : &h1b[0][0];
            #pragma unroll
            for (int i4 = 0; i4 < 12; ++i4) {
                float w0 = W1v[i4*4], w1 = W1v[i4*4+1], w2 = W1v[i4*4+2], w3 = W1v[i4*4+3];
                #pragma unroll
                for (int b = 0; b < DBP; ++b) {
                    float4 xv = *reinterpret_cast<const float4*>(&srcB[b * 52 + i4 * 4]);
                    acc[b] += w0*xv.x + w1*xv.y + w2*xv.z + w3*xv.w;
                }
            }
            #pragma unroll
            for (int b = 0; b < DBP; ++b) acc[b] += __shfl_xor(acc[b], 1, 64);
            if (kh == 0) {
                #pragma unroll
                for (int b = 0; b < DBP; ++b) xch[g][u][b] = acc[b];
            }
        }
        __syncthreads();
        // ---- c1 update + ht1 ----
        #pragma unroll
        for (int hh = 0; hh < 2; ++hh) {
            int b = b2 + 8 * hh;
            float gi = xch[0][u2][b] + bs1[0];
            float gf = xch[1][u2][b] + bs1[1];
            float gc = xch[2][u2][b] + bs1[2];
            float go = xch[3][u2][b] + bs1[3];
            float si = fsigmoid(gi), sf = fsigmoid(gf), so = fsigmoid(go), tg = ftanh(gc);
            c1[hh] = sf * c1[hh] + si * tg;
            htl[b][u2] = so * ftanh(c1[hh]);
        }
        __syncthreads();
        // ---- partial proj1 ----
        if (lane < PROJ) {
            #pragma unroll
            for (int bb = 0; bb < 2; ++bb) {
                int b = 2 * w + bb;
                float s = 0.f;
                #pragma unroll
                for (int u4 = 0; u4 < 16; ++u4) {
                    float4 wv = *reinterpret_cast<const float4*>(&wsl1[lane][u4 * 4]);
                    float4 hv = *reinterpret_cast<const float4*>(&htl[b][u4 * 4]);
                    s += wv.x*hv.x + wv.y*hv.y + wv.z*hv.z + wv.w*hv.w;
                }
                PPb[(size_t)rg * (BATCH * PROJ) + (size_t)(bg * DBP + b) * PROJ + lane] = s;
            }
        }
        phase += 1;
        bsync(slots, rg, phase, tid);
    }

    // epilogue: PRED[FUT-1] = sum of PPb partials (this rg's 2 batches)
    if (tid < 2 * PROJ) {
        int bb = tid / PROJ, p = tid % PROJ;
        int bglob = bg * DBP + 2 * rg + bb;
        float s = 0.f;
        #pragma unroll
        for (int rr = 0; rr < DRG; ++rr)
            s += PPb[(size_t)rr * (BATCH * PROJ) + (size_t)bglob * PROJ + p];
        PRED[((size_t)(FUT - 1) * BATCH + bglob) * PROJ + p] = s;
    }
}

// ---------------- basis contractions ----------------
__global__ void k_final(const float* __restrict__ theta, const float* __restrict__ H1,
                        const float* __restrict__ PRED, float* __restrict__ out)
{
    int b = blockIdx.x;
    __shared__ float th[2 * PROJ];
    if (threadIdx.x < 2 * PROJ) th[threadIdx.x] = theta[(size_t)b * 2 * PROJ + threadIdx.x];
    __syncthreads();
    for (int t = threadIdx.x; t < SEQ; t += 256) {
        float s = 0.f;
        #pragma unroll
        for (int p = 0; p < PROJ; ++p) s += th[PROJ + p] * H1[((size_t)t * BATCH + b) * PROJ + p];
        out[(size_t)b * SEQ + t] = s;
    }
    for (int t = threadIdx.x; t < FUT; t += 256) {
        float s = 0.f;
        #pragma unroll
        for (int p = 0; p < PROJ; ++p) s += th[p] * PRED[((size_t)t * BATCH + b) * PROJ + p];
        out[(size_t)BATCH * SEQ + (size_t)b * FUT + t] = s;
    }
}

extern "C" void kernel_launch(void* const* d_in, const int* in_sizes, int n_in,
                              void* d_out, int out_size, void* d_ws, size_t ws_size,
                              hipStream_t stream)
{
    (void)in_sizes; (void)n_in; (void)out_size;
    const float* theta = (const float*)d_in[0];
    const float* xin   = (const float*)d_in[1];
    const float* xdec  = (const float*)d_in[2];
    const float* eW0i = (const float*)d_in[3];
    const float* eW0h = (const float*)d_in[4];
    const float* eb0i = (const float*)d_in[5];
    const float* eb0h = (const float*)d_in[6];
    const float* eW0r = (const float*)d_in[7];
    const float* eW1i = (const float*)d_in[8];
    const float* eW1h = (const float*)d_in[9];
    const float* eb1i = (const float*)d_in[10];
    const float* eb1h = (const float*)d_in[11];
    const float* eW1r = (const float*)d_in[12];
    const float* dW0i = (const float*)d_in[13];
    const float* dW0h = (const float*)d_in[14];
    const float* db0i = (const float*)d_in[15];
    const float* db0h = (const float*)d_in[16];
    const float* dW0r = (const float*)d_in[17];
    const float* dW1i = (const float*)d_in[18];
    const float* dW1h = (const float*)d_in[19];
    const float* db1i = (const float*)d_in[20];
    const float* db1h = (const float*)d_in[21];
    const float* dW1r = (const float*)d_in[22];

    float* ws = (float*)d_ws;
    size_t off = 0;
    float* H0   = ws + off; off += (size_t)SEQ * BATCH * PROJ;
    float* H1   = ws + off; off += (size_t)SEQ * BATCH * PROJ;
    float* PRED = ws + off; off += (size_t)FUT * BATCH * PROJ;
    float* xT   = ws + off; off += (size_t)SEQ * BATCH * INF;
    float* hs   = ws + off; off += (size_t)2 * BATCH * PROJ;
    float* cs   = ws + off; off += (size_t)2 * BATCH * HID;
    float* prev = ws + off; off += (size_t)BATCH * PROJ;
    float* PPa  = ws + off; off += (size_t)2 * DRG * BATCH * PROJ;
    float* PPb  = ws + off; off += (size_t)DRG * BATCH * PROJ;
    off = (off + 63) & ~(size_t)63;
    unsigned* bar = (unsigned*)(ws + off); off += DBG * DRG * 16;
    float* Gbuf = ws + off;

    size_t availf = ws_size / sizeof(float);
    int CH = 64;
    while (CH > 1 && off + (size_t)CH * BATCH * G4 > availf) CH >>= 1;

    k_init<<<512, 256, 0, stream>>>(xin, hs, cs, prev);
    k_transpose<<<dim3(SEQ / 32, INF / 32, BATCH), dim3(32, 8), 0, stream>>>(xin, xT);

    for (int t0 = 0; t0 < SEQ; t0 += CH) {
        k_gates2<64><<<dim3(CH, 16), 512, 0, stream>>>(xT, t0 * BATCH, eW0i, eb0i, eb0h, Gbuf);
        k_rnn<<<BATCH, 512, 0, stream>>>(Gbuf, eW0h, eW0r, H0, hs, cs, t0, CH);
        k_gates2<48><<<dim3(CH, 16), 512, 0, stream>>>(H0, t0 * BATCH, eW1i, eb1i, eb1h, Gbuf);
        k_rnn<<<BATCH, 512, 0, stream>>>(Gbuf, eW1h, eW1r, H1, hs + BATCH * PROJ, cs + BATCH * HID, t0, CH);
    }

    hipMemsetAsync(bar, 0, DBG * DRG * 16 * sizeof(unsigned), stream);
    k_dec2<<<DRG * DBG, 512, 0, stream>>>(xdec, dW0i, dW0h, db0i, db0h, dW0r,
                                          dW1i, dW1h, db1i, db1h, dW1r,
                                          hs, cs, prev, PPa, PPb, PRED, bar);
    k_final<<<BATCH, 256, 0, stream>>>(theta, H1, PRED, (float*)d_out);
}

// Round 4
// 11168.130 us; speedup vs baseline: 1.2213x; 1.2213x over previous
//
#include <hip/hip_runtime.h>
#include <cstdint>
#include <cstddef>

#define BATCH 128
#define INF   64
#define OUTF  16
#define SEQ   512
#define FUT   96
#define HID   512
#define G4    2048   // 4*HID
#define PROJ  48

// decoder decomposition
#define DRG 8    // unit groups (64 units each)
#define DBG 8    // batch groups (16 batches each)
#define DUP 64   // units per rg
#define DBP 16   // batches per bg

__device__ __forceinline__ float fsigmoid(float x) {
    float e = __builtin_amdgcn_exp2f(-1.4426950408889634f * x);
    return __builtin_amdgcn_rcpf(1.0f + e);
}
__device__ __forceinline__ float ftanh(float x) {
    float e = __builtin_amdgcn_exp2f(2.8853900817779268f * x);
    return 1.0f - 2.0f * __builtin_amdgcn_rcpf(1.0f + e);
}

// cache-bypassing (LLC-coherent) data movement for cross-WG traffic.
// No fences anywhere: these never sit in the non-coherent L1/L2.
__device__ __forceinline__ float gload(const float* p) {
    return __hip_atomic_load(p, __ATOMIC_RELAXED, __HIP_MEMORY_SCOPE_AGENT);
}
__device__ __forceinline__ void gstore(float* p, float v) {
    __hip_atomic_store(p, v, __ATOMIC_RELAXED, __HIP_MEMORY_SCOPE_AGENT);
}

// barrier among DRG WGs of one chain: per-WG flag slots (64B apart), parallel
// stores + parallel polls, monotonically increasing phase, no fences.
// Ordering: each wave drains vmcnt before s_barrier (compiler-enforced), so all
// data gstores are LLC-visible before tid0 publishes the flag.
__device__ __forceinline__ void bsync(unsigned* slots, int rg, unsigned phase, int tid) {
    asm volatile("s_waitcnt vmcnt(0)" ::: "memory");
    __syncthreads();
    if (tid == 0)
        __hip_atomic_store(&slots[rg * 16], phase, __ATOMIC_RELAXED, __HIP_MEMORY_SCOPE_AGENT);
    if (tid < DRG) {
        while (__hip_atomic_load(&slots[tid * 16], __ATOMIC_RELAXED, __HIP_MEMORY_SCOPE_AGENT) < phase)
            __builtin_amdgcn_s_sleep(1);
    }
    __syncthreads();
    asm volatile("" ::: "memory");
}

// ---------------- init: zero states, build first_prev ----------------
__global__ void k_init(const float* __restrict__ x, float* __restrict__ hs,
                       float* __restrict__ cs, float* __restrict__ prev) {
    int idx = blockIdx.x * 256 + threadIdx.x;
    if (idx < 2 * BATCH * PROJ) hs[idx] = 0.f;
    if (idx < 2 * BATCH * HID)  cs[idx] = 0.f;
    if (idx < BATCH * PROJ) {
        int b = idx / PROJ, p = idx % PROJ;
        prev[idx] = x[(size_t)b * INF * SEQ + (size_t)p * SEQ + (SEQ - 1)];
    }
}

// ---------------- transpose x[b][k][t] -> xT[(t*B+b)*INF + k] ----------------
__global__ void k_transpose(const float* __restrict__ x, float* __restrict__ xT) {
    __shared__ float tile[32][33];
    int b  = blockIdx.z;
    int t0 = blockIdx.x * 32;
    int k0 = blockIdx.y * 32;
    int tx = threadIdx.x, ty = threadIdx.y; // 32 x 8
    #pragma unroll
    for (int i = 0; i < 4; ++i) {
        int k = k0 + ty + 8 * i;
        tile[ty + 8 * i][tx] = x[(size_t)b * INF * SEQ + (size_t)k * SEQ + t0 + tx];
    }
    __syncthreads();
    #pragma unroll
    for (int i = 0; i < 4; ++i) {
        int t = t0 + ty + 8 * i;
        xT[((size_t)t * BATCH + b) * INF + k0 + tx] = tile[tx][ty + 8 * i];
    }
}

// ---------------- input-gates GEMM: K-resident (K=64 or 48) ----------------
template<int K>
__global__ __launch_bounds__(512) void k_gates2(
    const float* __restrict__ A, int row0,
    const float* __restrict__ W, const float* __restrict__ bih,
    const float* __restrict__ bhh, float* __restrict__ G)
{
    __shared__ float Ast[128][K + 4];
    __shared__ float Wst[K][132];
    const int tid = threadIdx.x;
    const int rbase = blockIdx.x * 128;
    const int cb = blockIdx.y * 128;

    #pragma unroll
    for (int i = 0; i < K / 16; ++i) {
        int idx = tid + i * 512;
        int r = idx / (K / 4), kq = idx % (K / 4);
        float4 v = *reinterpret_cast<const float4*>(&A[(size_t)(row0 + rbase + r) * K + kq * 4]);
        *reinterpret_cast<float4*>(&Ast[r][kq * 4]) = v;
    }
    #pragma unroll
    for (int i = 0; i < K / 16; ++i) {
        int idx = tid + i * 512;
        int c = idx / (K / 4), kq = idx % (K / 4);
        float4 v = *reinterpret_cast<const float4*>(&W[(size_t)(cb + c) * K + kq * 4]);
        Wst[kq * 4 + 0][c] = v.x; Wst[kq * 4 + 1][c] = v.y;
        Wst[kq * 4 + 2][c] = v.z; Wst[kq * 4 + 3][c] = v.w;
    }
    __syncthreads();

    const int cg = tid & 31;
    const int rg = tid >> 5;
    float acc[8][4];
    #pragma unroll
    for (int j = 0; j < 8; ++j)
        #pragma unroll
        for (int i = 0; i < 4; ++i) acc[j][i] = 0.f;

    #pragma unroll
    for (int k4 = 0; k4 < K / 4; ++k4) {
        float4 w0 = *reinterpret_cast<const float4*>(&Wst[k4 * 4 + 0][cg * 4]);
        float4 w1 = *reinterpret_cast<const float4*>(&Wst[k4 * 4 + 1][cg * 4]);
        float4 w2 = *reinterpret_cast<const float4*>(&Wst[k4 * 4 + 2][cg * 4]);
        float4 w3 = *reinterpret_cast<const float4*>(&Wst[k4 * 4 + 3][cg * 4]);
        #pragma unroll
        for (int j = 0; j < 8; ++j) {
            float4 a = *reinterpret_cast<const float4*>(&Ast[rg * 8 + j][k4 * 4]);
            acc[j][0] += a.x * w0.x + a.y * w1.x + a.z * w2.x + a.w * w3.x;
            acc[j][1] += a.x * w0.y + a.y * w1.y + a.z * w2.y + a.w * w3.y;
            acc[j][2] += a.x * w0.z + a.y * w1.z + a.z * w2.z + a.w * w3.z;
            acc[j][3] += a.x * w0.w + a.y * w1.w + a.z * w2.w + a.w * w3.w;
        }
    }
    int c0 = cb + cg * 4;
    float4 bv;
    bv.x = bih[c0] + bhh[c0];         bv.y = bih[c0 + 1] + bhh[c0 + 1];
    bv.z = bih[c0 + 2] + bhh[c0 + 2]; bv.w = bih[c0 + 3] + bhh[c0 + 3];
    #pragma unroll
    for (int j = 0; j < 8; ++j) {
        float4 o;
        o.x = acc[j][0] + bv.x; o.y = acc[j][1] + bv.y;
        o.z = acc[j][2] + bv.z; o.w = acc[j][3] + bv.w;
        *reinterpret_cast<float4*>(&G[(size_t)(rbase + rg * 8 + j) * G4 + c0]) = o;
    }
}

// ---------------- encoder recurrent, layer-fused dispatch ----------------
// grid 2*BATCH: WGs [0,128) run layer A params (chunk c), WGs [128,256) run
// layer B params (chunk c-1) -- software pipeline across the two LSTM layers.
__global__ __launch_bounds__(512) void k_rnn2(
    const float* __restrict__ G0, const float* __restrict__ Whh0,
    const float* __restrict__ Whr0, float* __restrict__ Hout0,
    float* __restrict__ h_state0, float* __restrict__ c_state0, int t0a, int nt0,
    const float* __restrict__ G1, const float* __restrict__ Whh1,
    const float* __restrict__ Whr1, float* __restrict__ Hout1,
    float* __restrict__ h_state1, float* __restrict__ c_state1, int t0b, int nt1)
{
    const bool second = blockIdx.x >= BATCH;
    const int  b      = second ? blockIdx.x - BATCH : blockIdx.x;
    const int  nt     = second ? nt1 : nt0;
    if (nt == 0) return;
    const int  t0     = second ? t0b : t0a;
    const float* G    = second ? G1 : G0;
    const float* Whh  = second ? Whh1 : Whh0;
    const float* Whr  = second ? Whr1 : Whr0;
    float* Hout       = second ? Hout1 : Hout0;
    float* h_state    = second ? h_state1 : h_state0;
    float* c_state    = second ? c_state1 : c_state0;

    __shared__ float whr_lo[PROJ][256];
    __shared__ __align__(16) float ht_lds[HID];
    __shared__ __align__(16) float h_cur[PROJ];
    int j = threadIdx.x;
    int wave = j >> 6, lane = j & 63;

    float wI[PROJ], wF[PROJ], wG[PROJ], wO[PROJ];
    #pragma unroll
    for (int k4 = 0; k4 < 12; ++k4) {
        float4 vi = *reinterpret_cast<const float4*>(&Whh[(size_t)j * PROJ + 4 * k4]);
        float4 vf = *reinterpret_cast<const float4*>(&Whh[(size_t)(j + HID) * PROJ + 4 * k4]);
        float4 vg = *reinterpret_cast<const float4*>(&Whh[(size_t)(j + 2 * HID) * PROJ + 4 * k4]);
        float4 vo = *reinterpret_cast<const float4*>(&Whh[(size_t)(j + 3 * HID) * PROJ + 4 * k4]);
        wI[4*k4+0]=vi.x; wI[4*k4+1]=vi.y; wI[4*k4+2]=vi.z; wI[4*k4+3]=vi.w;
        wF[4*k4+0]=vf.x; wF[4*k4+1]=vf.y; wF[4*k4+2]=vf.z; wF[4*k4+3]=vf.w;
        wG[4*k4+0]=vg.x; wG[4*k4+1]=vg.y; wG[4*k4+2]=vg.z; wG[4*k4+3]=vg.w;
        wO[4*k4+0]=vo.x; wO[4*k4+1]=vo.y; wO[4*k4+2]=vo.z; wO[4*k4+3]=vo.w;
    }
    for (int idx = j; idx < PROJ * 256; idx += 512) {
        int p = idx >> 8, jj = idx & 255;
        whr_lo[p][jj] = Whr[(size_t)p * HID + jj];
    }
    float wr[6][4];
    #pragma unroll
    for (int q = 0; q < 6; ++q)
        #pragma unroll
        for (int m = 0; m < 4; ++m)
            wr[q][m] = Whr[(size_t)(wave * 6 + q) * HID + 256 + lane + 64 * m];

    float c = c_state[(size_t)b * HID + j];
    if (j < PROJ) h_cur[j] = h_state[(size_t)b * PROJ + j];
    __syncthreads();

    const float* Gr = G + (size_t)b * G4;
    float gi = Gr[j], gf = Gr[j + HID], gg = Gr[j + 2 * HID], go = Gr[j + 3 * HID];

    for (int ct = 0; ct < nt; ++ct) {
        float ai = gi, af = gf, ag = gg, ao = go;
        #pragma unroll
        for (int k4 = 0; k4 < 12; ++k4) {
            float4 h4 = *reinterpret_cast<const float4*>(&h_cur[4 * k4]);
            ai += wI[4*k4+0]*h4.x + wI[4*k4+1]*h4.y + wI[4*k4+2]*h4.z + wI[4*k4+3]*h4.w;
            af += wF[4*k4+0]*h4.x + wF[4*k4+1]*h4.y + wF[4*k4+2]*h4.z + wF[4*k4+3]*h4.w;
            ag += wG[4*k4+0]*h4.x + wG[4*k4+1]*h4.y + wG[4*k4+2]*h4.z + wG[4*k4+3]*h4.w;
            ao += wO[4*k4+0]*h4.x + wO[4*k4+1]*h4.y + wO[4*k4+2]*h4.z + wO[4*k4+3]*h4.w;
        }
        if (ct + 1 < nt) {
            const float* Gn = G + ((size_t)(ct + 1) * BATCH + b) * G4;
            gi = Gn[j]; gf = Gn[j + HID]; gg = Gn[j + 2 * HID]; go = Gn[j + 3 * HID];
        }
        float si = fsigmoid(ai), sf = fsigmoid(af), so = fsigmoid(ao), tg = ftanh(ag);
        c = sf * c + si * tg;
        ht_lds[j] = so * ftanh(c);
        __syncthreads();
        float rq[6];
        #pragma unroll
        for (int q = 0; q < 6; ++q) {
            int p = wave * 6 + q;
            float s = 0.f;
            #pragma unroll
            for (int m = 0; m < 4; ++m) s += whr_lo[p][lane + 64 * m] * ht_lds[lane + 64 * m];
            #pragma unroll
            for (int m = 0; m < 4; ++m) s += wr[q][m] * ht_lds[256 + lane + 64 * m];
            #pragma unroll
            for (int o = 32; o; o >>= 1) s += __shfl_xor(s, o, 64);
            rq[q] = s;
        }
        if (lane == 0) {
            int t = t0 + ct;
            #pragma unroll
            for (int q = 0; q < 6; ++q) {
                h_cur[wave * 6 + q] = rq[q];
                Hout[((size_t)t * BATCH + b) * PROJ + wave * 6 + q] = rq[q];
            }
        }
        __syncthreads();
    }
    c_state[(size_t)b * HID + j] = c;
    if (j < PROJ) h_state[(size_t)b * PROJ + j] = h_cur[j];
}

// ---------------- decoder v3: R3 structure + relaxed-atomic exchange ----------------
__global__ __launch_bounds__(512) void k_dec3(
    const float* __restrict__ xdec,
    const float* __restrict__ Wih0, const float* __restrict__ Whh0,
    const float* __restrict__ bih0, const float* __restrict__ bhh0,
    const float* __restrict__ Whr0,
    const float* __restrict__ Wih1, const float* __restrict__ Whh1,
    const float* __restrict__ bih1, const float* __restrict__ bhh1,
    const float* __restrict__ Whr1,
    const float* __restrict__ hs, const float* __restrict__ cs,
    const float* __restrict__ prev0,
    float* __restrict__ PPa,    // [2][DRG][BATCH][48]
    float* __restrict__ PPb,    // [DRG][BATCH][48]
    float* __restrict__ PRED,   // [FUT][BATCH][48]
    unsigned* __restrict__ bar) // [DBG][DRG*16]
{
    const int bg  = blockIdx.x & 7;   // chain id; bid%8 targets same-XCD placement
    const int rg  = blockIdx.x >> 3;
    const int tid = threadIdx.x;
    const int r  = tid >> 1;
    const int kh = tid & 1;
    const int g  = r >> 6;
    const int u  = r & 63;
    const int grow = g * HID + rg * DUP + u;
    const int u2 = tid >> 3;
    const int b2 = tid & 7;
    const int uglob = rg * DUP + u2;
    const int w = tid >> 6, lane = tid & 63;

    __shared__ float inp0[DBP][120];  // [h0(0..47) | prev(48..95) | x(96..111)]
    __shared__ float h1b[DBP][52];
    __shared__ float h0n[DBP][52];
    __shared__ float xch[4][DUP][17];
    __shared__ float htl[DBP][68];
    __shared__ float wslT0[DUP][52];  // transposed: [u][p] -> conflict-free reads
    __shared__ float wslT1[DUP][52];

    float W0v[56], W1v[48];
    #pragma unroll
    for (int kk = 0; kk < 56; ++kk) {
        int k = kh * 56 + kk;
        W0v[kk] = (k < 48) ? Whh0[(size_t)grow * 48 + k]
                           : Wih0[(size_t)grow * 64 + (k - 48)];
    }
    #pragma unroll
    for (int kk = 0; kk < 48; ++kk) {
        int k = kh * 48 + kk;
        W1v[kk] = (k < 48) ? Whh1[(size_t)grow * 48 + k]
                           : Wih1[(size_t)grow * 48 + (k - 48)];
    }
    for (int i = tid; i < PROJ * DUP; i += 512) {
        int p = i >> 6, uu = i & 63;
        wslT0[uu][p] = Whr0[(size_t)p * HID + rg * DUP + uu];
        wslT1[uu][p] = Whr1[(size_t)p * HID + rg * DUP + uu];
    }
    float bs0[4], bs1[4];
    #pragma unroll
    for (int gg = 0; gg < 4; ++gg) {
        bs0[gg] = bih0[gg * HID + uglob] + bhh0[gg * HID + uglob];
        bs1[gg] = bih1[gg * HID + uglob] + bhh1[gg * HID + uglob];
    }
    float c0[2], c1[2];
    #pragma unroll
    for (int hh = 0; hh < 2; ++hh) {
        int bglob = bg * DBP + b2 + 8 * hh;
        c0[hh] = cs[(size_t)bglob * HID + uglob];
        c1[hh] = cs[(size_t)(BATCH + bglob) * HID + uglob];
    }
    __syncthreads();

    unsigned* slots = bar + bg * (DRG * 16);
    unsigned phase = 0;

    for (int t = 0; t < FUT; ++t) {
        // ================= PHASE A =================
        if (t == 0) {
            for (int i = tid; i < DBP * PROJ; i += 512) {
                int b = i / PROJ, p = i % PROJ;
                int bglob = bg * DBP + b;
                inp0[b][p]      = hs[(size_t)bglob * PROJ + p];
                inp0[b][48 + p] = prev0[(size_t)bglob * PROJ + p];
                h1b[b][p]       = hs[(size_t)(BATCH + bglob) * PROJ + p];
            }
        } else {
            const float* pa = PPa + (size_t)((t - 1) & 1) * (DRG * BATCH * PROJ);
            for (int i = tid; i < 2 * DBP * PROJ; i += 512) {
                int which = (i >= DBP * PROJ);
                int idx = which ? i - DBP * PROJ : i;
                int b = idx / PROJ, p = idx % PROJ;
                int bglob = bg * DBP + b;
                const float* src = which ? PPb : pa;
                float s = 0.f;
                #pragma unroll
                for (int rr = 0; rr < DRG; ++rr)
                    s += gload(&src[(size_t)rr * (BATCH * PROJ) + (size_t)bglob * PROJ + p]);
                if (which) { inp0[b][48 + p] = s; h1b[b][p] = s; }
                else        inp0[b][p] = s;
            }
        }
        if (tid < DBP * OUTF) {
            int b = tid >> 4, f = tid & 15;
            inp0[b][96 + f] = xdec[(size_t)(bg * DBP + b) * (OUTF * FUT) + (size_t)f * FUT + t];
        }
        __syncthreads();
        if (t > 0 && tid < 2 * PROJ) {
            int bb = tid / PROJ, p = tid % PROJ;
            int bl = 2 * rg + bb;
            PRED[((size_t)(t - 1) * BATCH + bg * DBP + bl) * PROJ + p] = h1b[bl][p];
        }
        // ---- L0 gates ----
        {
            float acc[DBP];
            #pragma unroll
            for (int b = 0; b < DBP; ++b) acc[b] = 0.f;
            const float* srcA = &inp0[0][0] + kh * 56;
            #pragma unroll
            for (int i4 = 0; i4 < 14; ++i4) {
                float w0 = W0v[i4*4], w1 = W0v[i4*4+1], w2 = W0v[i4*4+2], w3 = W0v[i4*4+3];
                #pragma unroll
                for (int b = 0; b < DBP; ++b) {
                    float4 xv = *reinterpret_cast<const float4*>(&srcA[b * 120 + i4 * 4]);
                    acc[b] += w0*xv.x + w1*xv.y + w2*xv.z + w3*xv.w;
                }
            }
            #pragma unroll
            for (int b = 0; b < DBP; ++b) acc[b] += __shfl_xor(acc[b], 1, 64);
            if (kh == 0) {
                #pragma unroll
                for (int b = 0; b < DBP; ++b) xch[g][u][b] = acc[b];
            }
        }
        __syncthreads();
        // ---- c0 update + ht0 ----
        #pragma unroll
        for (int hh = 0; hh < 2; ++hh) {
            int b = b2 + 8 * hh;
            float gi = xch[0][u2][b] + bs0[0];
            float gf = xch[1][u2][b] + bs0[1];
            float gc = xch[2][u2][b] + bs0[2];
            float go = xch[3][u2][b] + bs0[3];
            float si = fsigmoid(gi), sf = fsigmoid(gf), so = fsigmoid(go), tg = ftanh(gc);
            c0[hh] = sf * c0[hh] + si * tg;
            htl[b][u2] = so * ftanh(c0[hh]);
        }
        __syncthreads();
        // ---- partial proj0 ----
        if (lane < PROJ) {
            float* dstb = PPa + (size_t)(t & 1) * (DRG * BATCH * PROJ)
                        + (size_t)rg * (BATCH * PROJ);
            #pragma unroll
            for (int bb = 0; bb < 2; ++bb) {
                int b = 2 * w + bb;
                float s = 0.f;
                #pragma unroll
                for (int u4 = 0; u4 < 16; ++u4) {
                    float4 hv = *reinterpret_cast<const float4*>(&htl[b][u4 * 4]);
                    s += wslT0[u4*4+0][lane]*hv.x + wslT0[u4*4+1][lane]*hv.y
                       + wslT0[u4*4+2][lane]*hv.z + wslT0[u4*4+3][lane]*hv.w;
                }
                gstore(&dstb[(size_t)(bg * DBP + b) * PROJ + lane], s);
            }
        }
        phase += 1;
        bsync(slots, rg, phase, tid);

        // ================= PHASE B =================
        {
            const float* pa2 = PPa + (size_t)(t & 1) * (DRG * BATCH * PROJ);
            for (int i = tid; i < DBP * PROJ; i += 512) {
                int b = i / PROJ, p = i % PROJ;
                float s = 0.f;
                #pragma unroll
                for (int rr = 0; rr < DRG; ++rr)
                    s += gload(&pa2[(size_t)rr * (BATCH * PROJ) + (size_t)(bg * DBP + b) * PROJ + p]);
                h0n[b][p] = s;
            }
        }
        __syncthreads();
        // ---- L1 gates (kh=0: Whh1 x h1b, kh=1: Wih1 x h0n) ----
        {
            float acc[DBP];
            #pragma unroll
            for (int b = 0; b < DBP; ++b) acc[b] = 0.f;
            const float* srcB = kh ? &h0n[0][0] : &h1b[0][0];
            #pragma unroll
            for (int i4 = 0; i4 < 12; ++i4) {
                float w0 = W1v[i4*4], w1 = W1v[i4*4+1], w2 = W1v[i4*4+2], w3 = W1v[i4*4+3];
                #pragma unroll
                for (int b = 0; b < DBP; ++b) {
                    float4 xv = *reinterpret_cast<const float4*>(&srcB[b * 52 + i4 * 4]);
                    acc[b] += w0*xv.x + w1*xv.y + w2*xv.z + w3*xv.w;
                }
            }
            #pragma unroll
            for (int b = 0; b < DBP; ++b) acc[b] += __shfl_xor(acc[b], 1, 64);
            if (kh == 0) {
                #pragma unroll
                for (int b = 0; b < DBP; ++b) xch[g][u][b] = acc[b];
            }
        }
        __syncthreads();
        // ---- c1 update + ht1 ----
        #pragma unroll
        for (int hh = 0; hh < 2; ++hh) {
            int b = b2 + 8 * hh;
            float gi = xch[0][u2][b] + bs1[0];
            float gf = xch[1][u2][b] + bs1[1];
            float gc = xch[2][u2][b] + bs1[2];
            float go = xch[3][u2][b] + bs1[3];
            float si = fsigmoid(gi), sf = fsigmoid(gf), so = fsigmoid(go), tg = ftanh(gc);
            c1[hh] = sf * c1[hh] + si * tg;
            htl[b][u2] = so * ftanh(c1[hh]);
        }
        __syncthreads();
        // ---- partial proj1 ----
        if (lane < PROJ) {
            #pragma unroll
            for (int bb = 0; bb < 2; ++bb) {
                int b = 2 * w + bb;
                float s = 0.f;
                #pragma unroll
                for (int u4 = 0; u4 < 16; ++u4) {
                    float4 hv = *reinterpret_cast<const float4*>(&htl[b][u4 * 4]);
                    s += wslT1[u4*4+0][lane]*hv.x + wslT1[u4*4+1][lane]*hv.y
                       + wslT1[u4*4+2][lane]*hv.z + wslT1[u4*4+3][lane]*hv.w;
                }
                gstore(&PPb[(size_t)rg * (BATCH * PROJ) + (size_t)(bg * DBP + b) * PROJ + lane], s);
            }
        }
        phase += 1;
        bsync(slots, rg, phase, tid);
    }

    // epilogue: PRED[FUT-1]
    if (tid < 2 * PROJ) {
        int bb = tid / PROJ, p = tid % PROJ;
        int bglob = bg * DBP + 2 * rg + bb;
        float s = 0.f;
        #pragma unroll
        for (int rr = 0; rr < DRG; ++rr)
            s += gload(&PPb[(size_t)rr * (BATCH * PROJ) + (size_t)bglob * PROJ + p]);
        PRED[((size_t)(FUT - 1) * BATCH + bglob) * PROJ + p] = s;
    }
}

// ---------------- basis contractions ----------------
__global__ void k_final(const float* __restrict__ theta, const float* __restrict__ H1,
                        const float* __restrict__ PRED, float* __restrict__ out)
{
    int b = blockIdx.x;
    __shared__ float th[2 * PROJ];
    if (threadIdx.x < 2 * PROJ) th[threadIdx.x] = theta[(size_t)b * 2 * PROJ + threadIdx.x];
    __syncthreads();
    for (int t = threadIdx.x; t < SEQ; t += 256) {
        float s = 0.f;
        #pragma unroll
        for (int p = 0; p < PROJ; ++p) s += th[PROJ + p] * H1[((size_t)t * BATCH + b) * PROJ + p];
        out[(size_t)b * SEQ + t] = s;
    }
    for (int t = threadIdx.x; t < FUT; t += 256) {
        float s = 0.f;
        #pragma unroll
        for (int p = 0; p < PROJ; ++p) s += th[p] * PRED[((size_t)t * BATCH + b) * PROJ + p];
        out[(size_t)BATCH * SEQ + (size_t)b * FUT + t] = s;
    }
}

extern "C" void kernel_launch(void* const* d_in, const int* in_sizes, int n_in,
                              void* d_out, int out_size, void* d_ws, size_t ws_size,
                              hipStream_t stream)
{
    (void)in_sizes; (void)n_in; (void)out_size;
    const float* theta = (const float*)d_in[0];
    const float* xin   = (const float*)d_in[1];
    const float* xdec  = (const float*)d_in[2];
    const float* eW0i = (const float*)d_in[3];
    const float* eW0h = (const float*)d_in[4];
    const float* eb0i = (const float*)d_in[5];
    const float* eb0h = (const float*)d_in[6];
    const float* eW0r = (const float*)d_in[7];
    const float* eW1i = (const float*)d_in[8];
    const float* eW1h = (const float*)d_in[9];
    const float* eb1i = (const float*)d_in[10];
    const float* eb1h = (const float*)d_in[11];
    const float* eW1r = (const float*)d_in[12];
    const float* dW0i = (const float*)d_in[13];
    const float* dW0h = (const float*)d_in[14];
    const float* db0i = (const float*)d_in[15];
    const float* db0h = (const float*)d_in[16];
    const float* dW0r = (const float*)d_in[17];
    const float* dW1i = (const float*)d_in[18];
    const float* dW1h = (const float*)d_in[19];
    const float* db1i = (const float*)d_in[20];
    const float* db1h = (const float*)d_in[21];
    const float* dW1r = (const float*)d_in[22];

    float* ws = (float*)d_ws;
    size_t off = 0;
    float* H0   = ws + off; off += (size_t)SEQ * BATCH * PROJ;
    float* H1   = ws + off; off += (size_t)SEQ * BATCH * PROJ;
    float* PRED = ws + off; off += (size_t)FUT * BATCH * PROJ;
    float* xT   = ws + off; off += (size_t)SEQ * BATCH * INF;
    float* hs   = ws + off; off += (size_t)2 * BATCH * PROJ;
    float* cs   = ws + off; off += (size_t)2 * BATCH * HID;
    float* prev = ws + off; off += (size_t)BATCH * PROJ;
    float* PPa  = ws + off; off += (size_t)2 * DRG * BATCH * PROJ;
    float* PPb  = ws + off; off += (size_t)DRG * BATCH * PROJ;
    off = (off + 63) & ~(size_t)63;
    unsigned* bar = (unsigned*)(ws + off); off += DBG * DRG * 16;
    float* Gb0;
    float* Gb1;

    size_t availf = ws_size / sizeof(float);
    int CH = 64;
    while (CH > 1 && off + (size_t)2 * CH * BATCH * G4 > availf) CH >>= 1;
    Gb0 = ws + off;
    Gb1 = ws + off + (size_t)CH * BATCH * G4;
    int NC = SEQ / CH;

    k_init<<<512, 256, 0, stream>>>(xin, hs, cs, prev);
    k_transpose<<<dim3(SEQ / 32, INF / 32, BATCH), dim3(32, 8), 0, stream>>>(xin, xT);

    // software pipeline: F(c) = {L0 chunk c, L1 chunk c-1}
    k_gates2<64><<<dim3(CH, 16), 512, 0, stream>>>(xT, 0, eW0i, eb0i, eb0h, Gb0);
    for (int c = 0; c < NC; ++c) {
        int nt1 = (c > 0) ? CH : 0;
        int t0b = (c - 1) * CH;
        k_rnn2<<<2 * BATCH, 512, 0, stream>>>(
            Gb0, eW0h, eW0r, H0, hs, cs, c * CH, CH,
            Gb1, eW1h, eW1r, H1, hs + BATCH * PROJ, cs + BATCH * HID, t0b, nt1);
        k_gates2<48><<<dim3(CH, 16), 512, 0, stream>>>(H0, c * CH * BATCH, eW1i, eb1i, eb1h, Gb1);
        if (c + 1 < NC)
            k_gates2<64><<<dim3(CH, 16), 512, 0, stream>>>(xT, (c + 1) * CH * BATCH, eW0i, eb0i, eb0h, Gb0);
    }
    // epilogue: L1 on last chunk
    k_rnn2<<<2 * BATCH, 512, 0, stream>>>(
        Gb0, eW0h, eW0r, H0, hs, cs, 0, 0,
        Gb1, eW1h, eW1r, H1, hs + BATCH * PROJ, cs + BATCH * HID, (NC - 1) * CH, CH);

    hipMemsetAsync(bar, 0, DBG * DRG * 16 * sizeof(unsigned), stream);
    k_dec3<<<DRG * DBG, 512, 0, stream>>>(xdec, dW0i, dW0h, db0i, db0h, dW0r,
                                          dW1i, dW1h, db1i, db1h, dW1r,
                                          hs, cs, prev, PPa, PPb, PRED, bar);
    k_final<<<BATCH, 256, 0, stream>>>(theta, H1, PRED, (float*)d_out);
}

// Round 5
// 9466.858 us; speedup vs baseline: 1.4407x; 1.1797x over previous
//
#include <hip/hip_runtime.h>
#include <cstdint>
#include <cstddef>

#define BATCH 128
#define INF   64
#define OUTF  16
#define SEQ   512
#define FUT   96
#define HID   512
#define G4    2048   // 4*HID
#define PROJ  48
#define ECH   4      // encoder steps per chunk

// decoder decomposition
#define DRG 8    // unit groups (64 units each)
#define DBG 8    // batch groups (16 batches each)
#define DUP 64
#define DBP 16

__device__ __forceinline__ float fsigmoid(float x) {
    float e = __builtin_amdgcn_exp2f(-1.4426950408889634f * x);
    return __builtin_amdgcn_rcpf(1.0f + e);
}
__device__ __forceinline__ float ftanh(float x) {
    float e = __builtin_amdgcn_exp2f(2.8853900817779268f * x);
    return 1.0f - 2.0f * __builtin_amdgcn_rcpf(1.0f + e);
}

// LLC-coherent (cache-bypassing) data movement for cross-WG traffic. No fences.
__device__ __forceinline__ float gload(const float* p) {
    return __hip_atomic_load(p, __ATOMIC_RELAXED, __HIP_MEMORY_SCOPE_AGENT);
}
__device__ __forceinline__ void gstore(float* p, float v) {
    __hip_atomic_store(p, v, __ATOMIC_RELAXED, __HIP_MEMORY_SCOPE_AGENT);
}

// chain barrier: one arrival counter; tid0 adds then polls with backoff.
// Each wave drains its own vmcnt before s_barrier, so all prior gstores are
// LLC-visible before the arrival is published.
__device__ __forceinline__ void bsync(unsigned* ctr, unsigned target, int tid) {
    asm volatile("s_waitcnt vmcnt(0)" ::: "memory");
    __syncthreads();
    if (tid == 0) {
        __hip_atomic_fetch_add(ctr, 1u, __ATOMIC_RELAXED, __HIP_MEMORY_SCOPE_AGENT);
        while (__hip_atomic_load(ctr, __ATOMIC_RELAXED, __HIP_MEMORY_SCOPE_AGENT) < target)
            __builtin_amdgcn_s_sleep(8);
    }
    __syncthreads();
    asm volatile("" ::: "memory");
}

// ---------------- guarded transpose W[R][C] -> WT[C][R] ----------------
__global__ void k_wtrans(const float* __restrict__ W, float* __restrict__ WT,
                         int R, int C) {
    __shared__ float tile[32][33];
    int r0 = blockIdx.x * 32, c0 = blockIdx.y * 32;
    int tx = threadIdx.x, ty = threadIdx.y; // 32 x 8
    #pragma unroll
    for (int i = 0; i < 4; ++i) {
        int r = r0 + ty + 8 * i;
        if (r < R && c0 + tx < C) tile[ty + 8 * i][tx] = W[(size_t)r * C + c0 + tx];
    }
    __syncthreads();
    #pragma unroll
    for (int i = 0; i < 4; ++i) {
        int c = c0 + ty + 8 * i;
        if (c < C && r0 + tx < R) WT[(size_t)c * R + r0 + tx] = tile[tx][ty + 8 * i];
    }
}

// ---------------- persistent fused encoder ----------------
// 256 WGs: [0,128) = layer0 (input from x), [128,256) = layer1 (input from
// H0x, chunk-pipelined behind layer0 via per-batch flags). Input GEMM fused:
// per chunk of ECH steps, gates accumulate in registers from transposed WihT.
__global__ __launch_bounds__(512) void k_enc(
    const float* __restrict__ x,
    const float* __restrict__ WT0, const float* __restrict__ Whh0,
    const float* __restrict__ bih0, const float* __restrict__ bhh0,
    const float* __restrict__ Whr0,
    const float* __restrict__ WT1, const float* __restrict__ Whh1,
    const float* __restrict__ bih1, const float* __restrict__ bhh1,
    const float* __restrict__ Whr1,
    float* __restrict__ H0x,   // [SEQ][B][48] uncached exchange
    float* __restrict__ H1,    // [SEQ][B][48]
    float* __restrict__ hs, float* __restrict__ cs,
    unsigned* __restrict__ eflags)  // [B][16]
{
    const bool L1w = blockIdx.x >= BATCH;
    const int b = L1w ? blockIdx.x - BATCH : blockIdx.x;
    const int j = threadIdx.x;
    const int wave = j >> 6, lane = j & 63;
    const float* WT  = L1w ? WT1 : WT0;
    const float* Whh = L1w ? Whh1 : Whh0;
    const float* Whr = L1w ? Whr1 : Whr0;
    const float* bih = L1w ? bih1 : bih0;
    const float* bhh = L1w ? bhh1 : bhh0;
    const int K = L1w ? PROJ : INF;

    __shared__ float whr[PROJ][HID + 4];                 // 99 KB
    __shared__ __align__(16) float xs[ECH][INF + 4];
    __shared__ __align__(16) float ht_lds[HID];
    __shared__ __align__(16) float h_cur[PROJ];

    // one-time preloads
    float wI[PROJ], wF[PROJ], wG[PROJ], wO[PROJ];
    #pragma unroll
    for (int k4 = 0; k4 < 12; ++k4) {
        float4 vi = *reinterpret_cast<const float4*>(&Whh[(size_t)j * PROJ + 4 * k4]);
        float4 vf = *reinterpret_cast<const float4*>(&Whh[(size_t)(j + HID) * PROJ + 4 * k4]);
        float4 vg = *reinterpret_cast<const float4*>(&Whh[(size_t)(j + 2 * HID) * PROJ + 4 * k4]);
        float4 vo = *reinterpret_cast<const float4*>(&Whh[(size_t)(j + 3 * HID) * PROJ + 4 * k4]);
        wI[4*k4+0]=vi.x; wI[4*k4+1]=vi.y; wI[4*k4+2]=vi.z; wI[4*k4+3]=vi.w;
        wF[4*k4+0]=vf.x; wF[4*k4+1]=vf.y; wF[4*k4+2]=vf.z; wF[4*k4+3]=vf.w;
        wG[4*k4+0]=vg.x; wG[4*k4+1]=vg.y; wG[4*k4+2]=vg.z; wG[4*k4+3]=vg.w;
        wO[4*k4+0]=vo.x; wO[4*k4+1]=vo.y; wO[4*k4+2]=vo.z; wO[4*k4+3]=vo.w;
    }
    for (int idx = j; idx < PROJ * HID; idx += 512) {
        int p = idx >> 9, jj = idx & 511;
        whr[p][jj] = Whr[(size_t)p * HID + jj];
    }
    float bI = bih[j] + bhh[j];
    float bF = bih[j + HID] + bhh[j + HID];
    float bG = bih[j + 2 * HID] + bhh[j + 2 * HID];
    float bO = bih[j + 3 * HID] + bhh[j + 3 * HID];
    float c = 0.f;
    if (j < PROJ) h_cur[j] = 0.f;
    __syncthreads();

    for (int t0 = 0; t0 < SEQ; t0 += ECH) {
        // ---- stage chunk inputs ----
        if (!L1w) {
            if (j < INF * ECH) {
                int k = j >> 2, dt = j & 3;
                xs[dt][k] = x[(size_t)b * INF * SEQ + (size_t)k * SEQ + t0 + dt];
            }
        } else {
            if (j == 0) {
                unsigned need = (unsigned)(t0 / ECH) + 1;
                while (__hip_atomic_load(&eflags[b * 16], __ATOMIC_RELAXED,
                                         __HIP_MEMORY_SCOPE_AGENT) < need)
                    __builtin_amdgcn_s_sleep(2);
            }
            __syncthreads();
            asm volatile("" ::: "memory");
            if (j < PROJ * ECH) {
                int dt = j / PROJ, p = j % PROJ;
                xs[dt][p] = gload(&H0x[((size_t)(t0 + dt) * BATCH + b) * PROJ + p]);
            }
        }
        __syncthreads();

        // ---- fused input-gate GEMM (two gate-pair passes, coalesced WT) ----
        float a0[ECH], a1[ECH], a2[ECH], a3[ECH];
        #pragma unroll
        for (int dt = 0; dt < ECH; ++dt) { a0[dt] = bI; a1[dt] = bF; }
        for (int kq = 0; kq < K / 4; ++kq) {
            float wi0 = WT[(size_t)(kq*4+0) * G4 + j];
            float wi1 = WT[(size_t)(kq*4+1) * G4 + j];
            float wi2 = WT[(size_t)(kq*4+2) * G4 + j];
            float wi3 = WT[(size_t)(kq*4+3) * G4 + j];
            float wf0 = WT[(size_t)(kq*4+0) * G4 + HID + j];
            float wf1 = WT[(size_t)(kq*4+1) * G4 + HID + j];
            float wf2 = WT[(size_t)(kq*4+2) * G4 + HID + j];
            float wf3 = WT[(size_t)(kq*4+3) * G4 + HID + j];
            #pragma unroll
            for (int dt = 0; dt < ECH; ++dt) {
                float4 xv = *reinterpret_cast<const float4*>(&xs[dt][kq * 4]);
                a0[dt] += wi0*xv.x + wi1*xv.y + wi2*xv.z + wi3*xv.w;
                a1[dt] += wf0*xv.x + wf1*xv.y + wf2*xv.z + wf3*xv.w;
            }
        }
        #pragma unroll
        for (int dt = 0; dt < ECH; ++dt) { a2[dt] = bG; a3[dt] = bO; }
        for (int kq = 0; kq < K / 4; ++kq) {
            float wg0 = WT[(size_t)(kq*4+0) * G4 + 2 * HID + j];
            float wg1 = WT[(size_t)(kq*4+1) * G4 + 2 * HID + j];
            float wg2 = WT[(size_t)(kq*4+2) * G4 + 2 * HID + j];
            float wg3 = WT[(size_t)(kq*4+3) * G4 + 2 * HID + j];
            float wo0 = WT[(size_t)(kq*4+0) * G4 + 3 * HID + j];
            float wo1 = WT[(size_t)(kq*4+1) * G4 + 3 * HID + j];
            float wo2 = WT[(size_t)(kq*4+2) * G4 + 3 * HID + j];
            float wo3 = WT[(size_t)(kq*4+3) * G4 + 3 * HID + j];
            #pragma unroll
            for (int dt = 0; dt < ECH; ++dt) {
                float4 xv = *reinterpret_cast<const float4*>(&xs[dt][kq * 4]);
                a2[dt] += wg0*xv.x + wg1*xv.y + wg2*xv.z + wg3*xv.w;
                a3[dt] += wo0*xv.x + wo1*xv.y + wo2*xv.z + wo3*xv.w;
            }
        }

        // ---- recurrent steps ----
        #pragma unroll
        for (int dt = 0; dt < ECH; ++dt) {
            float ai = a0[dt], af = a1[dt], ag = a2[dt], ao = a3[dt];
            #pragma unroll
            for (int k4 = 0; k4 < 12; ++k4) {
                float4 h4 = *reinterpret_cast<const float4*>(&h_cur[4 * k4]);
                ai += wI[4*k4+0]*h4.x + wI[4*k4+1]*h4.y + wI[4*k4+2]*h4.z + wI[4*k4+3]*h4.w;
                af += wF[4*k4+0]*h4.x + wF[4*k4+1]*h4.y + wF[4*k4+2]*h4.z + wF[4*k4+3]*h4.w;
                ag += wG[4*k4+0]*h4.x + wG[4*k4+1]*h4.y + wG[4*k4+2]*h4.z + wG[4*k4+3]*h4.w;
                ao += wO[4*k4+0]*h4.x + wO[4*k4+1]*h4.y + wO[4*k4+2]*h4.z + wO[4*k4+3]*h4.w;
            }
            float si = fsigmoid(ai), sf = fsigmoid(af), so = fsigmoid(ao), tg = ftanh(ag);
            c = sf * c + si * tg;
            ht_lds[j] = so * ftanh(c);
            __syncthreads();
            float rq[6];
            #pragma unroll
            for (int q = 0; q < 6; ++q) {
                int p = wave * 6 + q;
                float s = 0.f;
                #pragma unroll
                for (int m = 0; m < 8; ++m)
                    s += whr[p][lane + 64 * m] * ht_lds[lane + 64 * m];
                #pragma unroll
                for (int o = 32; o; o >>= 1) s += __shfl_xor(s, o, 64);
                rq[q] = s;
            }
            if (lane == 0) {
                int t = t0 + dt;
                #pragma unroll
                for (int q = 0; q < 6; ++q) {
                    int p = wave * 6 + q;
                    float v = rq[q];
                    h_cur[p] = v;
                    if (!L1w) gstore(&H0x[((size_t)t * BATCH + b) * PROJ + p], v);
                    else      H1[((size_t)t * BATCH + b) * PROJ + p] = v;
                }
            }
            __syncthreads();
        }
        if (!L1w) {
            asm volatile("s_waitcnt vmcnt(0)" ::: "memory");
            __syncthreads();
            if (j == 0)
                __hip_atomic_store(&eflags[b * 16], (unsigned)(t0 / ECH) + 1,
                                   __ATOMIC_RELAXED, __HIP_MEMORY_SCOPE_AGENT);
        }
    }
    // final states for decoder
    cs[((size_t)(L1w ? BATCH : 0) + b) * HID + j] = c;
    if (j < PROJ) hs[((size_t)(L1w ? BATCH : 0) + b) * PROJ + j] = h_cur[j];
}

// ---------------- decoder: 8rg x 8bg, partial-proj, 2 counter-syncs/step ----------------
__global__ __launch_bounds__(512) void k_dec3(
    const float* __restrict__ xdec,
    const float* __restrict__ Wih0, const float* __restrict__ Whh0,
    const float* __restrict__ bih0, const float* __restrict__ bhh0,
    const float* __restrict__ Whr0,
    const float* __restrict__ Wih1, const float* __restrict__ Whh1,
    const float* __restrict__ bih1, const float* __restrict__ bhh1,
    const float* __restrict__ Whr1,
    const float* __restrict__ hs, const float* __restrict__ cs,
    const float* __restrict__ xin,   // for first_prev
    float* __restrict__ PPa,    // [2][DRG][BATCH][48]
    float* __restrict__ PPb,    // [DRG][BATCH][48]
    float* __restrict__ PRED,   // [FUT][BATCH][48]
    unsigned* __restrict__ bar) // [DBG][64]
{
    const int bg  = blockIdx.x & 7;
    const int rg  = blockIdx.x >> 3;
    const int tid = threadIdx.x;
    const int r  = tid >> 1;
    const int kh = tid & 1;
    const int g  = r >> 6;
    const int u  = r & 63;
    const int grow = g * HID + rg * DUP + u;
    const int u2 = tid >> 3;
    const int b2 = tid & 7;
    const int uglob = rg * DUP + u2;
    const int w = tid >> 6, lane = tid & 63;

    __shared__ float inp0[DBP][120];
    __shared__ float h1b[DBP][52];
    __shared__ float h0n[DBP][52];
    __shared__ float xch[4][DUP][17];
    __shared__ float htl[DBP][68];
    __shared__ float wslT0[DUP][52];
    __shared__ float wslT1[DUP][52];

    float W0v[56], W1v[48];
    #pragma unroll
    for (int kk = 0; kk < 56; ++kk) {
        int k = kh * 56 + kk;
        W0v[kk] = (k < 48) ? Whh0[(size_t)grow * 48 + k]
                           : Wih0[(size_t)grow * 64 + (k - 48)];
    }
    #pragma unroll
    for (int kk = 0; kk < 48; ++kk) {
        int k = kh * 48 + kk;
        W1v[kk] = (k < 48) ? Whh1[(size_t)grow * 48 + k]
                           : Wih1[(size_t)grow * 48 + (k - 48)];
    }
    for (int i = tid; i < PROJ * DUP; i += 512) {
        int p = i >> 6, uu = i & 63;
        wslT0[uu][p] = Whr0[(size_t)p * HID + rg * DUP + uu];
        wslT1[uu][p] = Whr1[(size_t)p * HID + rg * DUP + uu];
    }
    float bs0[4], bs1[4];
    #pragma unroll
    for (int gg = 0; gg < 4; ++gg) {
        bs0[gg] = bih0[gg * HID + uglob] + bhh0[gg * HID + uglob];
        bs1[gg] = bih1[gg * HID + uglob] + bhh1[gg * HID + uglob];
    }
    float c0[2], c1[2];
    #pragma unroll
    for (int hh = 0; hh < 2; ++hh) {
        int bglob = bg * DBP + b2 + 8 * hh;
        c0[hh] = cs[(size_t)bglob * HID + uglob];
        c1[hh] = cs[(size_t)(BATCH + bglob) * HID + uglob];
    }
    __syncthreads();

    unsigned* ctr = bar + bg * 64;
    unsigned phase = 0;

    for (int t = 0; t < FUT; ++t) {
        // ================= PHASE A =================
        if (t == 0) {
            for (int i = tid; i < DBP * PROJ; i += 512) {
                int b = i / PROJ, p = i % PROJ;
                int bglob = bg * DBP + b;
                inp0[b][p]      = hs[(size_t)bglob * PROJ + p];
                inp0[b][48 + p] = xin[(size_t)bglob * INF * SEQ + (size_t)p * SEQ + (SEQ - 1)];
                h1b[b][p]       = hs[(size_t)(BATCH + bglob) * PROJ + p];
            }
        } else {
            const float* pa = PPa + (size_t)((t - 1) & 1) * (DRG * BATCH * PROJ);
            for (int i = tid; i < 2 * DBP * PROJ; i += 512) {
                int which = (i >= DBP * PROJ);
                int idx = which ? i - DBP * PROJ : i;
                int b = idx / PROJ, p = idx % PROJ;
                int bglob = bg * DBP + b;
                const float* src = which ? PPb : pa;
                float s = 0.f;
                #pragma unroll
                for (int rr = 0; rr < DRG; ++rr)
                    s += gload(&src[(size_t)rr * (BATCH * PROJ) + (size_t)bglob * PROJ + p]);
                if (which) { inp0[b][48 + p] = s; h1b[b][p] = s; }
                else        inp0[b][p] = s;
            }
        }
        if (tid < DBP * OUTF) {
            int b = tid >> 4, f = tid & 15;
            inp0[b][96 + f] = xdec[(size_t)(bg * DBP + b) * (OUTF * FUT) + (size_t)f * FUT + t];
        }
        __syncthreads();
        if (t > 0 && tid < 2 * PROJ) {
            int bb = tid / PROJ, p = tid % PROJ;
            int bl = 2 * rg + bb;
            PRED[((size_t)(t - 1) * BATCH + bg * DBP + bl) * PROJ + p] = h1b[bl][p];
        }
        // ---- L0 gates ----
        {
            float acc[DBP];
            #pragma unroll
            for (int b = 0; b < DBP; ++b) acc[b] = 0.f;
            const float* srcA = &inp0[0][0] + kh * 56;
            #pragma unroll
            for (int i4 = 0; i4 < 14; ++i4) {
                float w0 = W0v[i4*4], w1 = W0v[i4*4+1], w2 = W0v[i4*4+2], w3 = W0v[i4*4+3];
                #pragma unroll
                for (int b = 0; b < DBP; ++b) {
                    float4 xv = *reinterpret_cast<const float4*>(&srcA[b * 120 + i4 * 4]);
                    acc[b] += w0*xv.x + w1*xv.y + w2*xv.z + w3*xv.w;
                }
            }
            #pragma unroll
            for (int b = 0; b < DBP; ++b) acc[b] += __shfl_xor(acc[b], 1, 64);
            if (kh == 0) {
                #pragma unroll
                for (int b = 0; b < DBP; ++b) xch[g][u][b] = acc[b];
            }
        }
        __syncthreads();
        #pragma unroll
        for (int hh = 0; hh < 2; ++hh) {
            int b = b2 + 8 * hh;
            float gi = xch[0][u2][b] + bs0[0];
            float gf = xch[1][u2][b] + bs0[1];
            float gc = xch[2][u2][b] + bs0[2];
            float go = xch[3][u2][b] + bs0[3];
            float si = fsigmoid(gi), sf = fsigmoid(gf), so = fsigmoid(go), tg = ftanh(gc);
            c0[hh] = sf * c0[hh] + si * tg;
            htl[b][u2] = so * ftanh(c0[hh]);
        }
        __syncthreads();
        if (lane < PROJ) {
            float* dstb = PPa + (size_t)(t & 1) * (DRG * BATCH * PROJ)
                        + (size_t)rg * (BATCH * PROJ);
            #pragma unroll
            for (int bb = 0; bb < 2; ++bb) {
                int b = 2 * w + bb;
                float s = 0.f;
                #pragma unroll
                for (int u4 = 0; u4 < 16; ++u4) {
                    float4 hv = *reinterpret_cast<const float4*>(&htl[b][u4 * 4]);
                    s += wslT0[u4*4+0][lane]*hv.x + wslT0[u4*4+1][lane]*hv.y
                       + wslT0[u4*4+2][lane]*hv.z + wslT0[u4*4+3][lane]*hv.w;
                }
                gstore(&dstb[(size_t)(bg * DBP + b) * PROJ + lane], s);
            }
        }
        phase += 1;
        bsync(ctr, phase * DRG, tid);

        // ================= PHASE B =================
        {
            const float* pa2 = PPa + (size_t)(t & 1) * (DRG * BATCH * PROJ);
            for (int i = tid; i < DBP * PROJ; i += 512) {
                int b = i / PROJ, p = i % PROJ;
                float s = 0.f;
                #pragma unroll
                for (int rr = 0; rr < DRG; ++rr)
                    s += gload(&pa2[(size_t)rr * (BATCH * PROJ) + (size_t)(bg * DBP + b) * PROJ + p]);
                h0n[b][p] = s;
            }
        }
        __syncthreads();
        {
            float acc[DBP];
            #pragma unroll
            for (int b = 0; b < DBP; ++b) acc[b] = 0.f;
            const float* srcB = kh ? &h0n[0][0] : &h1b[0][0];
            #pragma unroll
            for (int i4 = 0; i4 < 12; ++i4) {
                float w0 = W1v[i4*4], w1 = W1v[i4*4+1], w2 = W1v[i4*4+2], w3 = W1v[i4*4+3];
                #pragma unroll
                for (int b = 0; b < DBP; ++b) {
                    float4 xv = *reinterpret_cast<const float4*>(&srcB[b * 52 + i4 * 4]);
                    acc[b] += w0*xv.x + w1*xv.y + w2*xv.z + w3*xv.w;
                }
            }
            #pragma unroll
            for (int b = 0; b < DBP; ++b) acc[b] += __shfl_xor(acc[b], 1, 64);
            if (kh == 0) {
                #pragma unroll
                for (int b = 0; b < DBP; ++b) xch[g][u][b] = acc[b];
            }
        }
        __syncthreads();
        #pragma unroll
        for (int hh = 0; hh < 2; ++hh) {
            int b = b2 + 8 * hh;
            float gi = xch[0][u2][b] + bs1[0];
            float gf = xch[1][u2][b] + bs1[1];
            float gc = xch[2][u2][b] + bs1[2];
            float go = xch[3][u2][b] + bs1[3];
            float si = fsigmoid(gi), sf = fsigmoid(gf), so = fsigmoid(go), tg = ftanh(gc);
            c1[hh] = sf * c1[hh] + si * tg;
            htl[b][u2] = so * ftanh(c1[hh]);
        }
        __syncthreads();
        if (lane < PROJ) {
            #pragma unroll
            for (int bb = 0; bb < 2; ++bb) {
                int b = 2 * w + bb;
                float s = 0.f;
                #pragma unroll
                for (int u4 = 0; u4 < 16; ++u4) {
                    float4 hv = *reinterpret_cast<const float4*>(&htl[b][u4 * 4]);
                    s += wslT1[u4*4+0][lane]*hv.x + wslT1[u4*4+1][lane]*hv.y
                       + wslT1[u4*4+2][lane]*hv.z + wslT1[u4*4+3][lane]*hv.w;
                }
                gstore(&PPb[(size_t)rg * (BATCH * PROJ) + (size_t)(bg * DBP + b) * PROJ + lane], s);
            }
        }
        phase += 1;
        bsync(ctr, phase * DRG, tid);
    }

    if (tid < 2 * PROJ) {
        int bb = tid / PROJ, p = tid % PROJ;
        int bglob = bg * DBP + 2 * rg + bb;
        float s = 0.f;
        #pragma unroll
        for (int rr = 0; rr < DRG; ++rr)
            s += gload(&PPb[(size_t)rr * (BATCH * PROJ) + (size_t)bglob * PROJ + p]);
        PRED[((size_t)(FUT - 1) * BATCH + bglob) * PROJ + p] = s;
    }
}

// ---------------- basis contractions ----------------
__global__ void k_final(const float* __restrict__ theta, const float* __restrict__ H1,
                        const float* __restrict__ PRED, float* __restrict__ out)
{
    int b = blockIdx.x;
    __shared__ float th[2 * PROJ];
    if (threadIdx.x < 2 * PROJ) th[threadIdx.x] = theta[(size_t)b * 2 * PROJ + threadIdx.x];
    __syncthreads();
    for (int t = threadIdx.x; t < SEQ; t += 256) {
        float s = 0.f;
        #pragma unroll
        for (int p = 0; p < PROJ; ++p) s += th[PROJ + p] * H1[((size_t)t * BATCH + b) * PROJ + p];
        out[(size_t)b * SEQ + t] = s;
    }
    for (int t = threadIdx.x; t < FUT; t += 256) {
        float s = 0.f;
        #pragma unroll
        for (int p = 0; p < PROJ; ++p) s += th[p] * PRED[((size_t)t * BATCH + b) * PROJ + p];
        out[(size_t)BATCH * SEQ + (size_t)b * FUT + t] = s;
    }
}

extern "C" void kernel_launch(void* const* d_in, const int* in_sizes, int n_in,
                              void* d_out, int out_size, void* d_ws, size_t ws_size,
                              hipStream_t stream)
{
    (void)in_sizes; (void)n_in; (void)out_size; (void)ws_size;
    const float* theta = (const float*)d_in[0];
    const float* xin   = (const float*)d_in[1];
    const float* xdec  = (const float*)d_in[2];
    const float* eW0i = (const float*)d_in[3];
    const float* eW0h = (const float*)d_in[4];
    const float* eb0i = (const float*)d_in[5];
    const float* eb0h = (const float*)d_in[6];
    const float* eW0r = (const float*)d_in[7];
    const float* eW1i = (const float*)d_in[8];
    const float* eW1h = (const float*)d_in[9];
    const float* eb1i = (const float*)d_in[10];
    const float* eb1h = (const float*)d_in[11];
    const float* eW1r = (const float*)d_in[12];
    const float* dW0i = (const float*)d_in[13];
    const float* dW0h = (const float*)d_in[14];
    const float* db0i = (const float*)d_in[15];
    const float* db0h = (const float*)d_in[16];
    const float* dW0r = (const float*)d_in[17];
    const float* dW1i = (const float*)d_in[18];
    const float* dW1h = (const float*)d_in[19];
    const float* db1i = (const float*)d_in[20];
    const float* db1h = (const float*)d_in[21];
    const float* dW1r = (const float*)d_in[22];

    float* ws = (float*)d_ws;
    size_t off = 0;
    float* H0x  = ws + off; off += (size_t)SEQ * BATCH * PROJ;
    float* H1   = ws + off; off += (size_t)SEQ * BATCH * PROJ;
    float* PRED = ws + off; off += (size_t)FUT * BATCH * PROJ;
    float* hs   = ws + off; off += (size_t)2 * BATCH * PROJ;
    float* cs   = ws + off; off += (size_t)2 * BATCH * HID;
    float* WT0  = ws + off; off += (size_t)INF * G4;
    float* WT1  = ws + off; off += (size_t)PROJ * G4;
    float* PPa  = ws + off; off += (size_t)2 * DRG * BATCH * PROJ;
    float* PPb  = ws + off; off += (size_t)DRG * BATCH * PROJ;
    off = (off + 63) & ~(size_t)63;
    unsigned* eflags = (unsigned*)(ws + off); off += BATCH * 16;
    unsigned* bar    = (unsigned*)(ws + off); off += DBG * 64;

    hipMemsetAsync(eflags, 0, (BATCH * 16 + DBG * 64) * sizeof(unsigned), stream);
    k_wtrans<<<dim3(G4 / 32, 2), dim3(32, 8), 0, stream>>>(eW0i, WT0, G4, INF);
    k_wtrans<<<dim3(G4 / 32, 2), dim3(32, 8), 0, stream>>>(eW1i, WT1, G4, PROJ);
    k_enc<<<2 * BATCH, 512, 0, stream>>>(xin,
                                         WT0, eW0h, eb0i, eb0h, eW0r,
                                         WT1, eW1h, eb1i, eb1h, eW1r,
                                         H0x, H1, hs, cs, eflags);
    k_dec3<<<DRG * DBG, 512, 0, stream>>>(xdec, dW0i, dW0h, db0i, db0h, dW0r,
                                          dW1i, dW1h, db1i, db1h, dW1r,
                                          hs, cs, xin, PPa, PPb, PRED, bar);
    k_final<<<BATCH, 256, 0, stream>>>(theta, H1, PRED, (float*)d_out);
}

// Round 7
// 9288.713 us; speedup vs baseline: 1.4684x; 1.0192x over previous
//
#include <hip/hip_runtime.h>
#include <cstdint>
#include <cstddef>

#define BATCH 128
#define INF   64
#define OUTF  16
#define SEQ   512
#define FUT   96
#define HID   512
#define G4    2048
#define PROJ  48
#define ECH   4

#define DRG 8
#define DBG 8
#define DUP 64
#define DBP 16

typedef float f32x4 __attribute__((ext_vector_type(4)));

__device__ __forceinline__ float fsigmoid(float x) {
    float e = __builtin_amdgcn_exp2f(-1.4426950408889634f * x);
    return __builtin_amdgcn_rcpf(1.0f + e);
}
__device__ __forceinline__ float ftanh(float x) {
    float e = __builtin_amdgcn_exp2f(2.8853900817779268f * x);
    return 1.0f - 2.0f * __builtin_amdgcn_rcpf(1.0f + e);
}

// scalar LLC-coherent ops (cross-WG)
__device__ __forceinline__ float gload(const float* p) {
    return __hip_atomic_load(p, __ATOMIC_RELAXED, __HIP_MEMORY_SCOPE_AGENT);
}
__device__ __forceinline__ void gstore(float* p, float v) {
    __hip_atomic_store(p, v, __ATOMIC_RELAXED, __HIP_MEMORY_SCOPE_AGENT);
}

// coherent vector gather: sum of 8 partials at p + rr*stride, fixed tree order.
__device__ __forceinline__ f32x4 gsum8(const float* p, size_t stride) {
    f32x4 a0, a1, a2, a3, a4, a5, a6, a7;
    asm volatile(
        "global_load_dwordx4 %0, %8, off sc0 sc1\n\t"
        "global_load_dwordx4 %1, %9, off sc0 sc1\n\t"
        "global_load_dwordx4 %2, %10, off sc0 sc1\n\t"
        "global_load_dwordx4 %3, %11, off sc0 sc1\n\t"
        "global_load_dwordx4 %4, %12, off sc0 sc1\n\t"
        "global_load_dwordx4 %5, %13, off sc0 sc1\n\t"
        "global_load_dwordx4 %6, %14, off sc0 sc1\n\t"
        "global_load_dwordx4 %7, %15, off sc0 sc1\n\t"
        "s_waitcnt vmcnt(0)"
        : "=&v"(a0), "=&v"(a1), "=&v"(a2), "=&v"(a3),
          "=&v"(a4), "=&v"(a5), "=&v"(a6), "=&v"(a7)
        : "v"(p), "v"(p + stride), "v"(p + 2 * stride), "v"(p + 3 * stride),
          "v"(p + 4 * stride), "v"(p + 5 * stride), "v"(p + 6 * stride),
          "v"(p + 7 * stride)
        : "memory");
    return ((a0 + a1) + (a2 + a3)) + ((a4 + a5) + (a6 + a7));
}

// chain barrier: one arrival counter; tid0 adds then polls with backoff.
__device__ __forceinline__ void bsync(unsigned* ctr, unsigned target, int tid) {
    asm volatile("s_waitcnt vmcnt(0)" ::: "memory");
    __syncthreads();
    if (tid == 0) {
        __hip_atomic_fetch_add(ctr, 1u, __ATOMIC_RELAXED, __HIP_MEMORY_SCOPE_AGENT);
        while (__hip_atomic_load(ctr, __ATOMIC_RELAXED, __HIP_MEMORY_SCOPE_AGENT) < target)
            __builtin_amdgcn_s_sleep(4);
    }
    __syncthreads();
    asm volatile("" ::: "memory");
}

// ---------------- guarded transpose W[R][C] -> WT[C][R] ----------------
__global__ void k_wtrans(const float* __restrict__ W, float* __restrict__ WT,
                         int R, int C) {
    __shared__ float tile[32][33];
    int r0 = blockIdx.x * 32, c0 = blockIdx.y * 32;
    int tx = threadIdx.x, ty = threadIdx.y;
    #pragma unroll
    for (int i = 0; i < 4; ++i) {
        int r = r0 + ty + 8 * i;
        if (r < R && c0 + tx < C) tile[ty + 8 * i][tx] = W[(size_t)r * C + c0 + tx];
    }
    __syncthreads();
    #pragma unroll
    for (int i = 0; i < 4; ++i) {
        int c = c0 + ty + 8 * i;
        if (c < C && r0 + tx < R) WT[(size_t)c * R + r0 + tx] = tile[tx][ty + 8 * i];
    }
}

// ---------------- persistent fused encoder ----------------
__global__ __launch_bounds__(512, 2) void k_enc(
    const float* __restrict__ x,
    const float* __restrict__ WT0, const float* __restrict__ Whh0,
    const float* __restrict__ bih0, const float* __restrict__ bhh0,
    const float* __restrict__ Whr0,
    const float* __restrict__ WT1, const float* __restrict__ Whh1,
    const float* __restrict__ bih1, const float* __restrict__ bhh1,
    const float* __restrict__ Whr1,
    float* __restrict__ H0x, float* __restrict__ H1,
    float* __restrict__ hs, float* __restrict__ cs,
    unsigned* __restrict__ eflags)
{
    const bool L1w = blockIdx.x >= BATCH;
    const int b = L1w ? blockIdx.x - BATCH : blockIdx.x;
    const int j = threadIdx.x;
    const int wave = j >> 6, lane = j & 63;
    const float* WT  = L1w ? WT1 : WT0;
    const float* Whh = L1w ? Whh1 : Whh0;
    const float* Whr = L1w ? Whr1 : Whr0;
    const float* bih = L1w ? bih1 : bih0;
    const float* bhh = L1w ? bhh1 : bhh0;
    const int K = L1w ? PROJ : INF;

    __shared__ float whr[PROJ][HID + 4];
    __shared__ __align__(16) float xs[ECH][INF + 4];
    __shared__ __align__(16) float ht_lds[HID];
    __shared__ __align__(16) float h_cur[PROJ];

    float wI[PROJ], wF[PROJ], wG[PROJ], wO[PROJ];
    #pragma unroll
    for (int k4 = 0; k4 < 12; ++k4) {
        float4 vi = *reinterpret_cast<const float4*>(&Whh[(size_t)j * PROJ + 4 * k4]);
        float4 vf = *reinterpret_cast<const float4*>(&Whh[(size_t)(j + HID) * PROJ + 4 * k4]);
        float4 vg = *reinterpret_cast<const float4*>(&Whh[(size_t)(j + 2 * HID) * PROJ + 4 * k4]);
        float4 vo = *reinterpret_cast<const float4*>(&Whh[(size_t)(j + 3 * HID) * PROJ + 4 * k4]);
        wI[4*k4+0]=vi.x; wI[4*k4+1]=vi.y; wI[4*k4+2]=vi.z; wI[4*k4+3]=vi.w;
        wF[4*k4+0]=vf.x; wF[4*k4+1]=vf.y; wF[4*k4+2]=vf.z; wF[4*k4+3]=vf.w;
        wG[4*k4+0]=vg.x; wG[4*k4+1]=vg.y; wG[4*k4+2]=vg.z; wG[4*k4+3]=vg.w;
        wO[4*k4+0]=vo.x; wO[4*k4+1]=vo.y; wO[4*k4+2]=vo.z; wO[4*k4+3]=vo.w;
    }
    for (int idx = j; idx < PROJ * HID; idx += 512) {
        int p = idx >> 9, jj = idx & 511;
        whr[p][jj] = Whr[(size_t)p * HID + jj];
    }
    float bI = bih[j] + bhh[j];
    float bF = bih[j + HID] + bhh[j + HID];
    float bG = bih[j + 2 * HID] + bhh[j + 2 * HID];
    float bO = bih[j + 3 * HID] + bhh[j + 3 * HID];
    float c = 0.f;
    if (j < PROJ) h_cur[j] = 0.f;
    __syncthreads();

    for (int t0 = 0; t0 < SEQ; t0 += ECH) {
        if (!L1w) {
            if (j < INF * ECH) {
                int k = j >> 2, dt = j & 3;
                xs[dt][k] = x[(size_t)b * INF * SEQ + (size_t)k * SEQ + t0 + dt];
            }
        } else {
            if (j == 0) {
                unsigned need = (unsigned)(t0 / ECH) + 1;
                while (__hip_atomic_load(&eflags[b * 16], __ATOMIC_RELAXED,
                                         __HIP_MEMORY_SCOPE_AGENT) < need)
                    __builtin_amdgcn_s_sleep(2);
            }
            __syncthreads();
            asm volatile("" ::: "memory");
            if (j < PROJ * ECH) {
                int dt = j / PROJ, p = j % PROJ;
                xs[dt][p] = gload(&H0x[((size_t)(t0 + dt) * BATCH + b) * PROJ + p]);
            }
        }
        __syncthreads();

        float a0[ECH], a1[ECH], a2[ECH], a3[ECH];
        #pragma unroll
        for (int dt = 0; dt < ECH; ++dt) { a0[dt] = bI; a1[dt] = bF; }
        for (int kq = 0; kq < K / 4; ++kq) {
            float wi0 = WT[(size_t)(kq*4+0) * G4 + j];
            float wi1 = WT[(size_t)(kq*4+1) * G4 + j];
            float wi2 = WT[(size_t)(kq*4+2) * G4 + j];
            float wi3 = WT[(size_t)(kq*4+3) * G4 + j];
            float wf0 = WT[(size_t)(kq*4+0) * G4 + HID + j];
            float wf1 = WT[(size_t)(kq*4+1) * G4 + HID + j];
            float wf2 = WT[(size_t)(kq*4+2) * G4 + HID + j];
            float wf3 = WT[(size_t)(kq*4+3) * G4 + HID + j];
            #pragma unroll
            for (int dt = 0; dt < ECH; ++dt) {
                float4 xv = *reinterpret_cast<const float4*>(&xs[dt][kq * 4]);
                a0[dt] += wi0*xv.x + wi1*xv.y + wi2*xv.z + wi3*xv.w;
                a1[dt] += wf0*xv.x + wf1*xv.y + wf2*xv.z + wf3*xv.w;
            }
        }
        #pragma unroll
        for (int dt = 0; dt < ECH; ++dt) { a2[dt] = bG; a3[dt] = bO; }
        for (int kq = 0; kq < K / 4; ++kq) {
            float wg0 = WT[(size_t)(kq*4+0) * G4 + 2 * HID + j];
            float wg1 = WT[(size_t)(kq*4+1) * G4 + 2 * HID + j];
            float wg2 = WT[(size_t)(kq*4+2) * G4 + 2 * HID + j];
            float wg3 = WT[(size_t)(kq*4+3) * G4 + 2 * HID + j];
            float wo0 = WT[(size_t)(kq*4+0) * G4 + 3 * HID + j];
            float wo1 = WT[(size_t)(kq*4+1) * G4 + 3 * HID + j];
            float wo2 = WT[(size_t)(kq*4+2) * G4 + 3 * HID + j];
            float wo3 = WT[(size_t)(kq*4+3) * G4 + 3 * HID + j];
            #pragma unroll
            for (int dt = 0; dt < ECH; ++dt) {
                float4 xv = *reinterpret_cast<const float4*>(&xs[dt][kq * 4]);
                a2[dt] += wg0*xv.x + wg1*xv.y + wg2*xv.z + wg3*xv.w;
                a3[dt] += wo0*xv.x + wo1*xv.y + wo2*xv.z + wo3*xv.w;
            }
        }

        #pragma unroll
        for (int dt = 0; dt < ECH; ++dt) {
            float ai = a0[dt], af = a1[dt], ag = a2[dt], ao = a3[dt];
            #pragma unroll
            for (int k4 = 0; k4 < 12; ++k4) {
                float4 h4 = *reinterpret_cast<const float4*>(&h_cur[4 * k4]);
                ai += wI[4*k4+0]*h4.x + wI[4*k4+1]*h4.y + wI[4*k4+2]*h4.z + wI[4*k4+3]*h4.w;
                af += wF[4*k4+0]*h4.x + wF[4*k4+1]*h4.y + wF[4*k4+2]*h4.z + wF[4*k4+3]*h4.w;
                ag += wG[4*k4+0]*h4.x + wG[4*k4+1]*h4.y + wG[4*k4+2]*h4.z + wG[4*k4+3]*h4.w;
                ao += wO[4*k4+0]*h4.x + wO[4*k4+1]*h4.y + wO[4*k4+2]*h4.z + wO[4*k4+3]*h4.w;
            }
            float si = fsigmoid(ai), sf = fsigmoid(af), so = fsigmoid(ao), tg = ftanh(ag);
            c = sf * c + si * tg;
            ht_lds[j] = so * ftanh(c);
            __syncthreads();
            float rq[6];
            #pragma unroll
            for (int q = 0; q < 6; ++q) {
                int p = wave * 6 + q;
                float s = 0.f;
                #pragma unroll
                for (int m = 0; m < 8; ++m)
                    s += whr[p][lane + 64 * m] * ht_lds[lane + 64 * m];
                #pragma unroll
                for (int o = 32; o; o >>= 1) s += __shfl_xor(s, o, 64);
                rq[q] = s;
            }
            if (lane == 0) {
                int t = t0 + dt;
                #pragma unroll
                for (int q = 0; q < 6; ++q) {
                    int p = wave * 6 + q;
                    float v = rq[q];
                    h_cur[p] = v;
                    if (!L1w) gstore(&H0x[((size_t)t * BATCH + b) * PROJ + p], v);
                    else      H1[((size_t)t * BATCH + b) * PROJ + p] = v;
                }
            }
            __syncthreads();
        }
        if (!L1w) {
            asm volatile("s_waitcnt vmcnt(0)" ::: "memory");
            __syncthreads();
            if (j == 0)
                __hip_atomic_store(&eflags[b * 16], (unsigned)(t0 / ECH) + 1,
                                   __ATOMIC_RELAXED, __HIP_MEMORY_SCOPE_AGENT);
        }
    }
    cs[((size_t)(L1w ? BATCH : 0) + b) * HID + j] = c;
    if (j < PROJ) hs[((size_t)(L1w ? BATCH : 0) + b) * PROJ + j] = h_cur[j];
}

// ---------------- decoder: 8rg x 8bg, vector coherent gathers ----------------
__global__ __launch_bounds__(512, 2) void k_dec3(
    const float* __restrict__ xdec,
    const float* __restrict__ Wih0, const float* __restrict__ Whh0,
    const float* __restrict__ bih0, const float* __restrict__ bhh0,
    const float* __restrict__ Whr0,
    const float* __restrict__ Wih1, const float* __restrict__ Whh1,
    const float* __restrict__ bih1, const float* __restrict__ bhh1,
    const float* __restrict__ Whr1,
    const float* __restrict__ hs, const float* __restrict__ cs,
    const float* __restrict__ xin,
    float* __restrict__ PPa,    // [2][DRG][BATCH][48]
    float* __restrict__ PPb,    // [DRG][BATCH][48]
    float* __restrict__ PRED,   // [FUT][BATCH][48]
    unsigned* __restrict__ bar) // [DBG][64]
{
    const int bg  = blockIdx.x & 7;
    const int rg  = blockIdx.x >> 3;
    const int tid = threadIdx.x;
    const int r  = tid >> 1;
    const int kh = tid & 1;
    const int g  = r >> 6;
    const int u  = r & 63;
    const int grow = g * HID + rg * DUP + u;
    const int u2 = tid >> 3;
    const int b2 = tid & 7;
    const int uglob = rg * DUP + u2;
    const int w = tid >> 6, lane = tid & 63;
    const size_t PSTR = (size_t)BATCH * PROJ;

    __shared__ __align__(16) float inp0[DBP][120];
    __shared__ __align__(16) float h1b[DBP][52];
    __shared__ __align__(16) float h0n[DBP][52];
    __shared__ float xch[4][DUP][17];
    __shared__ float htl[DBP][68];
    __shared__ float wslT0[DUP][52];
    __shared__ float wslT1[DUP][52];

    float W0v[56], W1v[48];
    #pragma unroll
    for (int kk = 0; kk < 56; ++kk) {
        int k = kh * 56 + kk;
        W0v[kk] = (k < 48) ? Whh0[(size_t)grow * 48 + k]
                           : Wih0[(size_t)grow * 64 + (k - 48)];
    }
    #pragma unroll
    for (int kk = 0; kk < 48; ++kk) {
        int k = kh * 48 + kk;
        W1v[kk] = (k < 48) ? Whh1[(size_t)grow * 48 + k]
                           : Wih1[(size_t)grow * 48 + (k - 48)];
    }
    for (int i = tid; i < PROJ * DUP; i += 512) {
        int p = i >> 6, uu = i & 63;
        wslT0[uu][p] = Whr0[(size_t)p * HID + rg * DUP + uu];
        wslT1[uu][p] = Whr1[(size_t)p * HID + rg * DUP + uu];
    }
    float bs0[4], bs1[4];
    #pragma unroll
    for (int gg = 0; gg < 4; ++gg) {
        bs0[gg] = bih0[gg * HID + uglob] + bhh0[gg * HID + uglob];
        bs1[gg] = bih1[gg * HID + uglob] + bhh1[gg * HID + uglob];
    }
    float c0[2], c1[2];
    #pragma unroll
    for (int hh = 0; hh < 2; ++hh) {
        int bglob = bg * DBP + b2 + 8 * hh;
        c0[hh] = cs[(size_t)bglob * HID + uglob];
        c1[hh] = cs[(size_t)(BATCH + bglob) * HID + uglob];
    }
    __syncthreads();

    unsigned* ctr = bar + bg * 64;
    unsigned phase = 0;

    for (int t = 0; t < FUT; ++t) {
        // ================= PHASE A =================
        if (t == 0) {
            for (int i = tid; i < DBP * PROJ; i += 512) {
                int b = i / PROJ, p = i % PROJ;
                int bglob = bg * DBP + b;
                inp0[b][p]      = hs[(size_t)bglob * PROJ + p];
                inp0[b][48 + p] = xin[(size_t)bglob * INF * SEQ + (size_t)p * SEQ + (SEQ - 1)];
                h1b[b][p]       = hs[(size_t)(BATCH + bglob) * PROJ + p];
            }
            if (tid < DBP * OUTF) {
                int b = tid >> 4, f = tid & 15;
                inp0[b][96 + f] = xdec[(size_t)(bg * DBP + b) * (OUTF * FUT) + (size_t)f * FUT + t];
            }
        } else {
            const float* pa = PPa + (size_t)((t - 1) & 1) * (DRG * PSTR);
            if (tid < 384) {
                int which = (tid >= 192);
                int idx = which ? tid - 192 : tid;
                int b = idx / 12, p = (idx % 12) * 4;
                int bglob = bg * DBP + b;
                const float* src = (which ? PPb : pa) + (size_t)bglob * PROJ + p;
                f32x4 s = gsum8(src, PSTR);
                if (which) {
                    *reinterpret_cast<f32x4*>(&inp0[b][48 + p]) = s;
                    *reinterpret_cast<f32x4*>(&h1b[b][p]) = s;
                } else {
                    *reinterpret_cast<f32x4*>(&inp0[b][p]) = s;
                }
            } else {
                // BUGFIX (R6): 128 threads cover all DBP*OUTF=256 (b,f) pairs
                #pragma unroll
                for (int rep = 0; rep < 2; ++rep) {
                    int i2 = (tid - 384) + rep * 128;
                    int b = i2 >> 4, f = i2 & 15;
                    inp0[b][96 + f] = xdec[(size_t)(bg * DBP + b) * (OUTF * FUT) + (size_t)f * FUT + t];
                }
            }
        }
        __syncthreads();
        if (t > 0 && tid < 2 * PROJ) {
            int bb = tid / PROJ, p = tid % PROJ;
            int bl = 2 * rg + bb;
            PRED[((size_t)(t - 1) * BATCH + bg * DBP + bl) * PROJ + p] = h1b[bl][p];
        }
        // ---- L0 gates ----
        {
            float acc[DBP];
            #pragma unroll
            for (int b = 0; b < DBP; ++b) acc[b] = 0.f;
            const float* srcA = &inp0[0][0] + kh * 56;
            #pragma unroll
            for (int i4 = 0; i4 < 14; ++i4) {
                float w0 = W0v[i4*4], w1 = W0v[i4*4+1], w2 = W0v[i4*4+2], w3 = W0v[i4*4+3];
                #pragma unroll
                for (int b = 0; b < DBP; ++b) {
                    float4 xv = *reinterpret_cast<const float4*>(&srcA[b * 120 + i4 * 4]);
                    acc[b] += w0*xv.x + w1*xv.y + w2*xv.z + w3*xv.w;
                }
            }
            #pragma unroll
            for (int b = 0; b < DBP; ++b) acc[b] += __shfl_xor(acc[b], 1, 64);
            if (kh == 0) {
                #pragma unroll
                for (int b = 0; b < DBP; ++b) xch[g][u][b] = acc[b];
            }
        }
        __syncthreads();
        #pragma unroll
        for (int hh = 0; hh < 2; ++hh) {
            int b = b2 + 8 * hh;
            float gi = xch[0][u2][b] + bs0[0];
            float gf = xch[1][u2][b] + bs0[1];
            float gc = xch[2][u2][b] + bs0[2];
            float go = xch[3][u2][b] + bs0[3];
            float si = fsigmoid(gi), sf = fsigmoid(gf), so = fsigmoid(go), tg = ftanh(gc);
            c0[hh] = sf * c0[hh] + si * tg;
            htl[b][u2] = so * ftanh(c0[hh]);
        }
        __syncthreads();
        if (lane < PROJ) {
            float* dstb = PPa + (size_t)(t & 1) * (DRG * PSTR) + (size_t)rg * PSTR;
            #pragma unroll
            for (int bb = 0; bb < 2; ++bb) {
                int b = 2 * w + bb;
                float s = 0.f;
                #pragma unroll
                for (int u4 = 0; u4 < 16; ++u4) {
                    float4 hv = *reinterpret_cast<const float4*>(&htl[b][u4 * 4]);
                    s += wslT0[u4*4+0][lane]*hv.x + wslT0[u4*4+1][lane]*hv.y
                       + wslT0[u4*4+2][lane]*hv.z + wslT0[u4*4+3][lane]*hv.w;
                }
                gstore(&dstb[(size_t)(bg * DBP + b) * PROJ + lane], s);
            }
        }
        phase += 1;
        bsync(ctr, phase * DRG, tid);

        // ================= PHASE B =================
        {
            const float* pa2 = PPa + (size_t)(t & 1) * (DRG * PSTR);
            if (tid < 192) {
                int b = tid / 12, p = (tid % 12) * 4;
                const float* src = pa2 + (size_t)(bg * DBP + b) * PROJ + p;
                f32x4 s = gsum8(src, PSTR);
                *reinterpret_cast<f32x4*>(&h0n[b][p]) = s;
            }
        }
        __syncthreads();
        {
            float acc[DBP];
            #pragma unroll
            for (int b = 0; b < DBP; ++b) acc[b] = 0.f;
            const float* srcB = kh ? &h0n[0][0] : &h1b[0][0];
            #pragma unroll
            for (int i4 = 0; i4 < 12; ++i4) {
                float w0 = W1v[i4*4], w1 = W1v[i4*4+1], w2 = W1v[i4*4+2], w3 = W1v[i4*4+3];
                #pragma unroll
                for (int b = 0; b < DBP; ++b) {
                    float4 xv = *reinterpret_cast<const float4*>(&srcB[b * 52 + i4 * 4]);
                    acc[b] += w0*xv.x + w1*xv.y + w2*xv.z + w3*xv.w;
                }
            }
            #pragma unroll
            for (int b = 0; b < DBP; ++b) acc[b] += __shfl_xor(acc[b], 1, 64);
            if (kh == 0) {
                #pragma unroll
                for (int b = 0; b < DBP; ++b) xch[g][u][b] = acc[b];
            }
        }
        __syncthreads();
        #pragma unroll
        for (int hh = 0; hh < 2; ++hh) {
            int b = b2 + 8 * hh;
            float gi = xch[0][u2][b] + bs1[0];
            float gf = xch[1][u2][b] + bs1[1];
            float gc = xch[2][u2][b] + bs1[2];
            float go = xch[3][u2][b] + bs1[3];
            float si = fsigmoid(gi), sf = fsigmoid(gf), so = fsigmoid(go), tg = ftanh(gc);
            c1[hh] = sf * c1[hh] + si * tg;
            htl[b][u2] = so * ftanh(c1[hh]);
        }
        __syncthreads();
        if (lane < PROJ) {
            #pragma unroll
            for (int bb = 0; bb < 2; ++bb) {
                int b = 2 * w + bb;
                float s = 0.f;
                #pragma unroll
                for (int u4 = 0; u4 < 16; ++u4) {
                    float4 hv = *reinterpret_cast<const float4*>(&htl[b][u4 * 4]);
                    s += wslT1[u4*4+0][lane]*hv.x + wslT1[u4*4+1][lane]*hv.y
                       + wslT1[u4*4+2][lane]*hv.z + wslT1[u4*4+3][lane]*hv.w;
                }
                gstore(&PPb[(size_t)rg * PSTR + (size_t)(bg * DBP + b) * PROJ + lane], s);
            }
        }
        phase += 1;
        bsync(ctr, phase * DRG, tid);
    }

    if (tid < 2 * PROJ) {
        int bb = tid / PROJ, p = tid % PROJ;
        int bglob = bg * DBP + 2 * rg + bb;
        float s = 0.f;
        #pragma unroll
        for (int rr = 0; rr < DRG; ++rr)
            s += gload(&PPb[(size_t)rr * PSTR + (size_t)bglob * PROJ + p]);
        PRED[((size_t)(FUT - 1) * BATCH + bglob) * PROJ + p] = s;
    }
}

// ---------------- basis contractions ----------------
__global__ void k_final(const float* __restrict__ theta, const float* __restrict__ H1,
                        const float* __restrict__ PRED, float* __restrict__ out)
{
    int b = blockIdx.x;
    __shared__ float th[2 * PROJ];
    if (threadIdx.x < 2 * PROJ) th[threadIdx.x] = theta[(size_t)b * 2 * PROJ + threadIdx.x];
    __syncthreads();
    for (int t = threadIdx.x; t < SEQ; t += 256) {
        float s = 0.f;
        #pragma unroll
        for (int p = 0; p < PROJ; ++p) s += th[PROJ + p] * H1[((size_t)t * BATCH + b) * PROJ + p];
        out[(size_t)b * SEQ + t] = s;
    }
    for (int t = threadIdx.x; t < FUT; t += 256) {
        float s = 0.f;
        #pragma unroll
        for (int p = 0; p < PROJ; ++p) s += th[p] * PRED[((size_t)t * BATCH + b) * PROJ + p];
        out[(size_t)BATCH * SEQ + (size_t)b * FUT + t] = s;
    }
}

extern "C" void kernel_launch(void* const* d_in, const int* in_sizes, int n_in,
                              void* d_out, int out_size, void* d_ws, size_t ws_size,
                              hipStream_t stream)
{
    (void)in_sizes; (void)n_in; (void)out_size; (void)ws_size;
    const float* theta = (const float*)d_in[0];
    const float* xin   = (const float*)d_in[1];
    const float* xdec  = (const float*)d_in[2];
    const float* eW0i = (const float*)d_in[3];
    const float* eW0h = (const float*)d_in[4];
    const float* eb0i = (const float*)d_in[5];
    const float* eb0h = (const float*)d_in[6];
    const float* eW0r = (const float*)d_in[7];
    const float* eW1i = (const float*)d_in[8];
    const float* eW1h = (const float*)d_in[9];
    const float* eb1i = (const float*)d_in[10];
    const float* eb1h = (const float*)d_in[11];
    const float* eW1r = (const float*)d_in[12];
    const float* dW0i = (const float*)d_in[13];
    const float* dW0h = (const float*)d_in[14];
    const float* db0i = (const float*)d_in[15];
    const float* db0h = (const float*)d_in[16];
    const float* dW0r = (const float*)d_in[17];
    const float* dW1i = (const float*)d_in[18];
    const float* dW1h = (const float*)d_in[19];
    const float* db1i = (const float*)d_in[20];
    const float* db1h = (const float*)d_in[21];
    const float* dW1r = (const float*)d_in[22];

    float* ws = (float*)d_ws;
    size_t off = 0;
    float* H0x  = ws + off; off += (size_t)SEQ * BATCH * PROJ;
    float* H1   = ws + off; off += (size_t)SEQ * BATCH * PROJ;
    float* PRED = ws + off; off += (size_t)FUT * BATCH * PROJ;
    float* hs   = ws + off; off += (size_t)2 * BATCH * PROJ;
    float* cs   = ws + off; off += (size_t)2 * BATCH * HID;
    float* WT0  = ws + off; off += (size_t)INF * G4;
    float* WT1  = ws + off; off += (size_t)PROJ * G4;
    float* PPa  = ws + off; off += (size_t)2 * DRG * BATCH * PROJ;
    float* PPb  = ws + off; off += (size_t)DRG * BATCH * PROJ;
    off = (off + 63) & ~(size_t)63;
    unsigned* eflags = (unsigned*)(ws + off); off += BATCH * 16;
    unsigned* bar    = (unsigned*)(ws + off); off += DBG * 64;

    hipMemsetAsync(eflags, 0, (BATCH * 16 + DBG * 64) * sizeof(unsigned), stream);
    k_wtrans<<<dim3(G4 / 32, 2), dim3(32, 8), 0, stream>>>(eW0i, WT0, G4, INF);
    k_wtrans<<<dim3(G4 / 32, 2), dim3(32, 8), 0, stream>>>(eW1i, WT1, G4, PROJ);
    k_enc<<<2 * BATCH, 512, 0, stream>>>(xin,
                                         WT0, eW0h, eb0i, eb0h, eW0r,
                                         WT1, eW1h, eb1i, eb1h, eW1r,
                                         H0x, H1, hs, cs, eflags);
    k_dec3<<<DRG * DBG, 512, 0, stream>>>(xdec, dW0i, dW0h, db0i, db0h, dW0r,
                                          dW1i, dW1h, db1i, db1h, dW1r,
                                          hs, cs, xin, PPa, PPb, PRED, bar);
    k_final<<<BATCH, 256, 0, stream>>>(theta, H1, PRED, (float*)d_out);
}